// Round 7
// baseline (233.061 us; speedup 1.0000x reference)
//
#include <hip/hip_runtime.h>
#include <hip/hip_bf16.h>
#include <hip/hip_fp16.h>

// GCN: 3 layers over fixed graph (N=100000 nodes, E=1600000 edges).
// CSR build via bucketed sort (512-node buckets, packed 4B payload, LDS
// cursors only). Gather aggs: branchless pipelined inner loop.
// Layer-0 GEMM on matrix cores (mfma 16x16x32 f16). Layer 2 commuted:
// out = (agg(X2)/deg)@W2 + b2, matvec fused into the final agg epilogue.

constexpr int NB_SHIFT = 9;          // 512 nodes per bucket
constexpr int EPB = 8192;            // edges per block in pass A/B
constexpr int MAXNB = 200;           // >= ceil(100000/512)=196

using half8   = __attribute__((ext_vector_type(8))) _Float16;
using floatx4 = __attribute__((ext_vector_type(4))) float;

// Pass A: per-block LDS histogram over buckets -> C_T[bucket][block] counts.
__global__ __launch_bounds__(256) void passA_hist(const int* __restrict__ dst, int* __restrict__ C_T,
                                                  int nb, int nblk, int n_edges) {
    __shared__ int h[MAXNB];
    for (int i = threadIdx.x; i < nb; i += 256) h[i] = 0;
    __syncthreads();
    const int e0 = blockIdx.x * EPB;
    const int e1 = min(e0 + EPB, n_edges);
    for (int i = e0 + threadIdx.x; i < e1; i += 256)
        atomicAdd(&h[dst[i] >> NB_SHIFT], 1);
    __syncthreads();
    for (int i = threadIdx.x; i < nb; i += 256)
        C_T[i * nblk + blockIdx.x] = h[i];
}

// Per-bucket exclusive scan across blocks (in place); row totals out.
__global__ __launch_bounds__(256) void bucket_prefix(int* __restrict__ C_T, int* __restrict__ totals,
                                                     int nblk) {
    __shared__ int s[256];
    const int b = blockIdx.x, t = threadIdx.x;
    int v = (t < nblk) ? C_T[b * nblk + t] : 0;
    s[t] = v; __syncthreads();
    for (int off = 1; off < 256; off <<= 1) {
        int x = (t >= off) ? s[t - off] : 0;
        __syncthreads();
        s[t] += x;
        __syncthreads();
    }
    if (t < nblk) C_T[b * nblk + t] = s[t] - v;
    if (t == 255) totals[b] = s[255];
}

// Exclusive scan of bucket totals -> base[nb+1]; also rowptr[n]=E.
__global__ __launch_bounds__(256) void scan_base(const int* __restrict__ totals, int* __restrict__ base_out,
                                                 int* __restrict__ rowptr, int nb, int n, int n_edges) {
    __shared__ int s[256];
    const int t = threadIdx.x;
    int v[4]; int ts = 0;
#pragma unroll
    for (int j = 0; j < 4; ++j) { int i = t * 4 + j; v[j] = (i < nb) ? totals[i] : 0; ts += v[j]; }
    s[t] = ts; __syncthreads();
    for (int off = 1; off < 256; off <<= 1) {
        int x = (t >= off) ? s[t - off] : 0;
        __syncthreads();
        s[t] += x;
        __syncthreads();
    }
    int run = s[t] - ts;
#pragma unroll
    for (int j = 0; j < 4; ++j) { int i = t * 4 + j; if (i < nb) base_out[i] = run; run += v[j]; }
    if (t == 255) base_out[nb] = s[255];
    if (t == 0) rowptr[n] = n_edges;
}

// Pass B: scatter packed (ldst<<17)|src into bucket order using LDS cursors.
__global__ __launch_bounds__(256) void passB_scatter(const int* __restrict__ src, const int* __restrict__ dst,
                                                     const int* __restrict__ C_T, const int* __restrict__ base,
                                                     int* __restrict__ sorted_pk, int nb, int nblk, int n_edges) {
    __shared__ int cur[MAXNB];
    const int blk = blockIdx.x;
    for (int i = threadIdx.x; i < nb; i += 256) cur[i] = base[i] + C_T[i * nblk + blk];
    __syncthreads();
    const int e0 = blk * EPB;
    const int e1 = min(e0 + EPB, n_edges);
    for (int i = e0 + threadIdx.x; i < e1; i += 256) {
        int d = dst[i];
        int p = atomicAdd(&cur[d >> NB_SHIFT], 1);
        sorted_pk[p] = ((d & 511) << 17) | src[i];
    }
}

// Pass C: per-bucket (512 nodes) counting sort in LDS -> rowptr, col, inv_deg.
__global__ __launch_bounds__(512) void passC_build(const int* __restrict__ sorted_pk, const int* __restrict__ base,
                                                   int* __restrict__ rowptr, int* __restrict__ col,
                                                   float* __restrict__ invd, int n) {
    __shared__ int degl[512];
    __shared__ int s[512];
    __shared__ int curl[512];
    const int b = blockIdx.x, t = threadIdx.x;
    const int node0 = b << NB_SHIFT;
    const int nn = min(512, n - node0);
    const int e0 = base[b], e1 = base[b + 1];
    degl[t] = 0;
    __syncthreads();
    for (int i = e0 + t; i < e1; i += 512)
        atomicAdd(&degl[sorted_pk[i] >> 17], 1);
    __syncthreads();
    int d = degl[t];
    s[t] = d; __syncthreads();
    for (int off = 1; off < 512; off <<= 1) {
        int x = (t >= off) ? s[t - off] : 0;
        __syncthreads();
        s[t] += x;
        __syncthreads();
    }
    int excl = s[t] - d;
    curl[t] = excl;
    if (t < nn) {
        rowptr[node0 + t] = e0 + excl;
        invd[node0 + t] = 1.0f / (float)(d > 0 ? d : 1);
    }
    __syncthreads();
    for (int i = e0 + t; i < e1; i += 512) {
        int pk = sorted_pk[i];
        int p = atomicAdd(&curl[pk >> 17], 1);
        col[e0 + p] = pk & 0x1FFFF;
    }
}

// ---- type helpers ----
__device__ inline float4 load4(const __half* p) {
    __half2 a = *(const __half2*)p;
    __half2 b = *(const __half2*)(p + 2);
    float2 fa = __half22float2(a), fb = __half22float2(b);
    return make_float4(fa.x, fa.y, fb.x, fb.y);
}
__device__ inline void store4(float* p, float x0, float x1, float x2, float x3) {
    *(float4*)p = make_float4(x0, x1, x2, x3);
}
__device__ inline void store4(__half* p, float x0, float x1, float x2, float x3) {
    union { __half h[4]; int2 i2; } u;
    u.h[0] = __float2half(x0); u.h[1] = __float2half(x1);
    u.h[2] = __float2half(x2); u.h[3] = __float2half(x3);
    *(int2*)p = u.i2;
}

// Gather-aggregate: one node per wave; lane = (edge_slot, feat_quad).
// Branchless pipelined loop (clamped col prefetch). 64 feats fp16.
// EPI: 0 = plain sum; 1 = relu(sum*inv_deg + bias).
template <int EPI>
__global__ __launch_bounds__(256) void agg_kernel(const __half* __restrict__ X, const int* __restrict__ col,
                                                  const int* __restrict__ rowptr,
                                                  const float* __restrict__ inv_deg,
                                                  const float* __restrict__ bias,
                                                  __half* __restrict__ out, int n) {
    constexpr int LPE = 16;          // lanes per edge
    constexpr int EPW = 4;           // edges per wave-issue
    const int node = blockIdx.x * 4 + (threadIdx.x >> 6);
    if (node >= n) return;
    const int lane = threadIdx.x & 63;
    const int eg = lane / LPE;
    const int fl = lane % LPE;
    const int s = rowptr[node], e = rowptr[node + 1];

    float ax = 0.f, ay = 0.f, az = 0.f, aw = 0.f;
    if (e > s) {
        int i = s + eg;
        const int nfull = (e - s) / EPW;
        int cc = col[min(i, e - 1)];
#pragma unroll 2
        for (int b = 0; b < nfull; ++b) {
            int cn = col[min(i + EPW, e - 1)];
            const __half* p = X + (size_t)cc * 64 + fl * 4;
            float2 f01 = __half22float2(*(const __half2*)p);
            float2 f23 = __half22float2(*(const __half2*)(p + 2));
            ax += f01.x; ay += f01.y; az += f23.x; aw += f23.y;
            cc = cn; i += EPW;
        }
        if (i < e) {
            const __half* p = X + (size_t)cc * 64 + fl * 4;
            float2 f01 = __half22float2(*(const __half2*)p);
            float2 f23 = __half22float2(*(const __half2*)(p + 2));
            ax += f01.x; ay += f01.y; az += f23.x; aw += f23.y;
        }
    }
#pragma unroll
    for (int m = LPE; m < 64; m <<= 1) {
        ax += __shfl_xor(ax, m);
        ay += __shfl_xor(ay, m);
        az += __shfl_xor(az, m);
        aw += __shfl_xor(aw, m);
    }
    if (eg == 0) {
        if (EPI != 0) {
            float sc = inv_deg[node];
            ax = fmaxf(ax * sc + bias[fl * 4 + 0], 0.f);
            ay = fmaxf(ay * sc + bias[fl * 4 + 1], 0.f);
            az = fmaxf(az * sc + bias[fl * 4 + 2], 0.f);
            aw = fmaxf(aw * sc + bias[fl * 4 + 3], 0.f);
        }
        store4(&out[(size_t)node * 64 + fl * 4], ax, ay, az, aw);
    }
}

// Final agg with fused matvec: out[node] = (agg(X2[node])/deg) @ W2 + b2.
// Gather identical to agg_kernel; epilogue: v (64) -> LDS, each lane does a
// 32-k partial of one of 32 output cols, folded with one shfl_xor(32).
__global__ __launch_bounds__(256) void agg_out_kernel(const __half* __restrict__ X2, const int* __restrict__ col,
                                                      const int* __restrict__ rowptr,
                                                      const float* __restrict__ inv_deg,
                                                      const float* __restrict__ W2, const float* __restrict__ b2,
                                                      float* __restrict__ out, int n) {
    __shared__ float W2s[64][33];
    __shared__ float vbuf[4][64];
    const int t = threadIdx.x;
#pragma unroll
    for (int l = 0; l < 8; ++l) {
        int o = t + l * 256;
        W2s[o >> 5][o & 31] = W2[o];
    }
    __syncthreads();

    const int node = blockIdx.x * 4 + (t >> 6);
    if (node >= n) return;
    const int wave = t >> 6, lane = t & 63;
    const int eg = lane >> 4, fl = lane & 15;   // LPE=16, EPW=4
    const int s = rowptr[node], e = rowptr[node + 1];

    float ax = 0.f, ay = 0.f, az = 0.f, aw = 0.f;
    if (e > s) {
        int i = s + eg;
        const int nfull = (e - s) / 4;
        int cc = col[min(i, e - 1)];
#pragma unroll 2
        for (int b = 0; b < nfull; ++b) {
            int cn = col[min(i + 4, e - 1)];
            const __half* p = X2 + (size_t)cc * 64 + fl * 4;
            float2 f01 = __half22float2(*(const __half2*)p);
            float2 f23 = __half22float2(*(const __half2*)(p + 2));
            ax += f01.x; ay += f01.y; az += f23.x; aw += f23.y;
            cc = cn; i += 4;
        }
        if (i < e) {
            const __half* p = X2 + (size_t)cc * 64 + fl * 4;
            float2 f01 = __half22float2(*(const __half2*)p);
            float2 f23 = __half22float2(*(const __half2*)(p + 2));
            ax += f01.x; ay += f01.y; az += f23.x; aw += f23.y;
        }
    }
#pragma unroll
    for (int m = 16; m < 64; m <<= 1) {
        ax += __shfl_xor(ax, m);
        ay += __shfl_xor(ay, m);
        az += __shfl_xor(az, m);
        aw += __shfl_xor(aw, m);
    }
    if (eg == 0) {
        float sc = inv_deg[node];
        vbuf[wave][fl * 4 + 0] = ax * sc;
        vbuf[wave][fl * 4 + 1] = ay * sc;
        vbuf[wave][fl * 4 + 2] = az * sc;
        vbuf[wave][fl * 4 + 3] = aw * sc;
    }
    // intra-wave LDS write->read; compiler inserts the lgkmcnt wait
    const int c = lane & 31, kh = (lane >> 5) * 32;
    float sum = 0.f;
#pragma unroll 8
    for (int k = 0; k < 32; ++k)
        sum += vbuf[wave][kh + k] * W2s[kh + k][c];
    sum += __shfl_xor(sum, 32);
    if (lane < 32) out[(size_t)node * 32 + c] = sum + b2[c];
}

// Transpose+convert W0 [256][64] f32 -> W0t [64][256] fp16.
__global__ __launch_bounds__(256) void cvtW0t(const float* __restrict__ W0, __half* __restrict__ W0t) {
    int o = blockIdx.x * 256 + threadIdx.x;   // 16384 elems
    int c = o >> 8, k = o & 255;
    W0t[o] = __float2half(W0[k * 64 + c]);
}

// Layer-0 GEMM on matrix cores: H[nrows x 64] = feat[nrows x 256] @ W0 (fp16 in, f32 acc).
__global__ __launch_bounds__(256) void gemm0_mfma(const float* __restrict__ A, const __half* __restrict__ W0t,
                                                  __half* __restrict__ out, int nrows) {
    constexpr int LDH = 280;
    __shared__ _Float16 As[64][LDH];
    __shared__ _Float16 Bs[64][LDH];
    const int t = threadIdx.x;
    const int wave = t >> 6, lane = t & 63;
    const int row0 = blockIdx.x * 64;

#pragma unroll
    for (int l = 0; l < 16; ++l) {
        int fid = t + l * 256;
        int r = fid >> 6, c4 = fid & 63;
        int grow = row0 + r;
        int gr = grow < nrows ? grow : 0;
        float4 v = *(const float4*)&A[(size_t)gr * 256 + c4 * 4];
        _Float16* p = &As[r][c4 * 4];
        p[0] = (_Float16)v.x; p[1] = (_Float16)v.y;
        p[2] = (_Float16)v.z; p[3] = (_Float16)v.w;
    }
#pragma unroll
    for (int l = 0; l < 8; ++l) {
        int fid = t + l * 256;
        int r = fid >> 5, c8 = fid & 31;
        *(half8*)&Bs[r][c8 * 8] = *(const half8*)&W0t[r * 256 + c8 * 8];
    }
    __syncthreads();

    const int ar = wave * 16 + (lane & 15);
    const int kh = (lane >> 4) * 8;
    floatx4 acc0 = {0.f, 0.f, 0.f, 0.f}, acc1 = acc0, acc2 = acc0, acc3 = acc0;
#pragma unroll
    for (int ks = 0; ks < 8; ++ks) {
        const int k0 = ks * 32 + kh;
        half8 a = *(half8*)&As[ar][k0];
        half8 b0 = *(half8*)&Bs[ 0 + (lane & 15)][k0];
        half8 b1 = *(half8*)&Bs[16 + (lane & 15)][k0];
        half8 b2 = *(half8*)&Bs[32 + (lane & 15)][k0];
        half8 b3 = *(half8*)&Bs[48 + (lane & 15)][k0];
        acc0 = __builtin_amdgcn_mfma_f32_16x16x32_f16(a, b0, acc0, 0, 0, 0);
        acc1 = __builtin_amdgcn_mfma_f32_16x16x32_f16(a, b1, acc1, 0, 0, 0);
        acc2 = __builtin_amdgcn_mfma_f32_16x16x32_f16(a, b2, acc2, 0, 0, 0);
        acc3 = __builtin_amdgcn_mfma_f32_16x16x32_f16(a, b3, acc3, 0, 0, 0);
    }

    const int cc = lane & 15;
    const int rb = wave * 16 + (lane >> 4) * 4;
#pragma unroll
    for (int i = 0; i < 4; ++i) {
        int r = row0 + rb + i;
        if (r < nrows) {
            __half* po = &out[(size_t)r * 64];
            po[ 0 + cc] = __float2half(acc0[i]);
            po[16 + cc] = __float2half(acc1[i]);
            po[32 + cc] = __float2half(acc2[i]);
            po[48 + cc] = __float2half(acc3[i]);
        }
    }
}

// Layer-1 GEMM: X2 = relu((A2@W1)*inv_deg + b1), fp16 in/out, f32 math.
__global__ __launch_bounds__(256) void gemm1_kernel(const __half* __restrict__ A2, const float* __restrict__ W1,
                                                    const float* __restrict__ b1, const float* __restrict__ inv_deg,
                                                    __half* __restrict__ out, int nrows) {
    __shared__ float As[64][68];
    __shared__ float W1s[64][64];
    const int t = threadIdx.x;
    const int row0 = blockIdx.x * 64;
    const int cg = t % 16, rg = t / 16;

#pragma unroll
    for (int l = 0; l < 4; ++l) {
        int fid = t + l * 256;
        int r = fid / 16, c4 = fid % 16;
        int grow = row0 + r;
        int gr = grow < nrows ? grow : 0;
        float4 v = load4(&A2[(size_t)gr * 64 + c4 * 4]);
        *(float4*)&As[r][c4 * 4] = v;
    }
#pragma unroll
    for (int l = 0; l < 4; ++l) {
        int fid = t + l * 256;
        int r = fid / 16, c4 = fid % 16;
        *(float4*)&W1s[r][c4 * 4] = *(const float4*)&W1[(size_t)r * 64 + c4 * 4];
    }
    __syncthreads();

    float acc[4][4] = {};
#pragma unroll 8
    for (int k = 0; k < 64; ++k) {
        float4 w = *(float4*)&W1s[k][cg * 4];
#pragma unroll
        for (int i = 0; i < 4; ++i) {
            float a = As[rg * 4 + i][k];
            acc[i][0] += a * w.x;
            acc[i][1] += a * w.y;
            acc[i][2] += a * w.z;
            acc[i][3] += a * w.w;
        }
    }

#pragma unroll
    for (int i = 0; i < 4; ++i) {
        int r = row0 + rg * 4 + i;
        if (r < nrows) {
            float sc = inv_deg[r];
            float x0 = fmaxf(acc[i][0] * sc + b1[cg * 4 + 0], 0.f);
            float x1 = fmaxf(acc[i][1] * sc + b1[cg * 4 + 1], 0.f);
            float x2 = fmaxf(acc[i][2] * sc + b1[cg * 4 + 2], 0.f);
            float x3 = fmaxf(acc[i][3] * sc + b1[cg * 4 + 3], 0.f);
            store4(&out[(size_t)r * 64 + cg * 4], x0, x1, x2, x3);
        }
    }
}

extern "C" void kernel_launch(void* const* d_in, const int* in_sizes, int n_in,
                              void* d_out, int out_size, void* d_ws, size_t ws_size,
                              hipStream_t stream) {
    const float* feat = (const float*)d_in[0];
    const float* W0   = (const float*)d_in[1];
    const float* b0   = (const float*)d_in[2];
    const float* W1   = (const float*)d_in[3];
    const float* b1   = (const float*)d_in[4];
    const float* W2   = (const float*)d_in[5];
    const float* b2   = (const float*)d_in[6];
    const int*   src  = (const int*)d_in[7];
    const int*   dstv = (const int*)d_in[8];

    const int n = in_sizes[0] / 256;   // 100000
    const int e = in_sizes[7];         // 1600000

    const int nb   = (n + 511) >> NB_SHIFT;        // 196 buckets
    const int nblk = (e + EPB - 1) / EPB;          // 196 blocks

    // Workspace carve-up (256B aligned).
    char* base_p = (char*)d_ws;
    size_t off = 0;
    auto alloc = [&](size_t bytes) -> char* {
        char* p = base_p + off;
        off += (bytes + 255) & ~(size_t)255;
        return p;
    };
    float*  invd   = (float*)alloc((size_t)n * 4);
    int*    rowptr = (int*)alloc((size_t)(n + 1) * 4);
    int*    bbase  = (int*)alloc((size_t)(MAXNB + 1) * 4);
    int*    totals = (int*)alloc((size_t)MAXNB * 4);
    __half* W0t    = (__half*)alloc((size_t)256 * 64 * 2);
    int*    col    = (int*)alloc((size_t)e * 4);          // C_T aliases col
    __half* bufH1  = (__half*)alloc((size_t)n * 64 * 2);  // H; later A2. sorted_pk aliases.
    __half* bufH2  = (__half*)alloc((size_t)n * 64 * 2);  // X1; later X2
    (void)ws_size;

    int* C_T       = col;           // nb*nblk ints (154KB) — dead before col is written
    int* sorted_pk = (int*)bufH1;   // e*4 B (6.4MB) — dead before gemm0 writes bufH1

    // --- CSR build (bucketed sort, no global atomics) ---
    passA_hist   <<<nblk, 256, 0, stream>>>(dstv, C_T, nb, nblk, e);
    bucket_prefix<<<nb,   256, 0, stream>>>(C_T, totals, nblk);
    scan_base    <<<1,    256, 0, stream>>>(totals, bbase, rowptr, nb, n, e);
    passB_scatter<<<nblk, 256, 0, stream>>>(src, dstv, C_T, bbase, sorted_pk, nb, nblk, e);
    passC_build  <<<nb,   512, 0, stream>>>(sorted_pk, bbase, rowptr, col, invd, n);
    cvtW0t       <<<64,   256, 0, stream>>>(W0, W0t);

    const int gemm_blocks = (n + 63) / 64;
    const int agg_blocks  = (n + 3) / 4;   // one wave per node, 4 waves/block

    // --- Layer 0: H = feat@W0 (MFMA fp16) ; X1 = relu(agg(H)*inv + b0) ---
    gemm0_mfma<<<gemm_blocks, 256, 0, stream>>>(feat, W0t, bufH1, n);
    agg_kernel<1><<<agg_blocks, 256, 0, stream>>>(bufH1, col, rowptr, invd, b0, bufH2, n);

    // --- Layer 1: A2 = agg(X1) ; X2 = relu((A2@W1)*inv + b1) ---
    agg_kernel<0><<<agg_blocks, 256, 0, stream>>>(bufH2, col, rowptr, nullptr, nullptr, bufH1, n);
    gemm1_kernel<<<gemm_blocks, 256, 0, stream>>>(bufH1, W1, b1, invd, bufH2, n);

    // --- Layer 2 (commuted): out = (agg(X2)/deg)@W2 + b2 ---
    agg_out_kernel<<<agg_blocks, 256, 0, stream>>>(bufH2, col, rowptr, invd, W2, b2, (float*)d_out, n);
}

// Round 8
// 226.149 us; speedup vs baseline: 1.0306x; 1.0306x over previous
//
#include <hip/hip_runtime.h>
#include <hip/hip_bf16.h>
#include <hip/hip_fp16.h>

// GCN: 3 layers over fixed graph (N=100000 nodes, E=1600000 edges).
// CSR build via bucketed sort (128-node buckets — R5-proven config).
// Gather aggs: branchless pipelined inner loop (~25cyc/edge floor).
// Layer-0 and layer-1 GEMMs on matrix cores (mfma 16x16x32 f16).
// Layer 2 commuted: out = (agg(X2)/deg)@W2 + b2 fused into final agg.

constexpr int NB_SHIFT = 7;          // 128 nodes per bucket
constexpr int EPB = 8192;            // edges per block in pass A/B
constexpr int MAXNB = 800;           // >= ceil(100000/128)=782

using half8   = __attribute__((ext_vector_type(8))) _Float16;
using floatx4 = __attribute__((ext_vector_type(4))) float;

// Pass A: per-block LDS histogram over buckets -> C_T[bucket][block] counts.
__global__ __launch_bounds__(256) void passA_hist(const int* __restrict__ dst, int* __restrict__ C_T,
                                                  int nb, int nblk, int n_edges) {
    __shared__ int h[MAXNB];
    for (int i = threadIdx.x; i < nb; i += 256) h[i] = 0;
    __syncthreads();
    const int e0 = blockIdx.x * EPB;
    const int e1 = min(e0 + EPB, n_edges);
    for (int i = e0 + threadIdx.x; i < e1; i += 256)
        atomicAdd(&h[dst[i] >> NB_SHIFT], 1);
    __syncthreads();
    for (int i = threadIdx.x; i < nb; i += 256)
        C_T[i * nblk + blockIdx.x] = h[i];
}

// Per-bucket exclusive scan across blocks (in place); row totals out.
__global__ __launch_bounds__(256) void bucket_prefix(int* __restrict__ C_T, int* __restrict__ totals,
                                                     int nblk) {
    __shared__ int s[256];
    const int b = blockIdx.x, t = threadIdx.x;
    int v = (t < nblk) ? C_T[b * nblk + t] : 0;
    s[t] = v; __syncthreads();
    for (int off = 1; off < 256; off <<= 1) {
        int x = (t >= off) ? s[t - off] : 0;
        __syncthreads();
        s[t] += x;
        __syncthreads();
    }
    if (t < nblk) C_T[b * nblk + t] = s[t] - v;
    if (t == 255) totals[b] = s[255];
}

// Exclusive scan of bucket totals -> base[nb+1]; also rowptr[n]=E.
__global__ __launch_bounds__(256) void scan_base(const int* __restrict__ totals, int* __restrict__ base_out,
                                                 int* __restrict__ rowptr, int nb, int n, int n_edges) {
    __shared__ int s[256];
    const int t = threadIdx.x;
    int v[4]; int ts = 0;
#pragma unroll
    for (int j = 0; j < 4; ++j) { int i = t * 4 + j; v[j] = (i < nb) ? totals[i] : 0; ts += v[j]; }
    s[t] = ts; __syncthreads();
    for (int off = 1; off < 256; off <<= 1) {
        int x = (t >= off) ? s[t - off] : 0;
        __syncthreads();
        s[t] += x;
        __syncthreads();
    }
    int run = s[t] - ts;
#pragma unroll
    for (int j = 0; j < 4; ++j) { int i = t * 4 + j; if (i < nb) base_out[i] = run; run += v[j]; }
    if (t == 255) base_out[nb] = s[255];
    if (t == 0) rowptr[n] = n_edges;
}

// Pass B: scatter packed (ldst<<17)|src into bucket order using LDS cursors.
__global__ __launch_bounds__(256) void passB_scatter(const int* __restrict__ src, const int* __restrict__ dst,
                                                     const int* __restrict__ C_T, const int* __restrict__ base,
                                                     int* __restrict__ sorted_pk, int nb, int nblk, int n_edges) {
    __shared__ int cur[MAXNB];
    const int blk = blockIdx.x;
    for (int i = threadIdx.x; i < nb; i += 256) cur[i] = base[i] + C_T[i * nblk + blk];
    __syncthreads();
    const int e0 = blk * EPB;
    const int e1 = min(e0 + EPB, n_edges);
    for (int i = e0 + threadIdx.x; i < e1; i += 256) {
        int d = dst[i];
        int p = atomicAdd(&cur[d >> NB_SHIFT], 1);
        sorted_pk[p] = ((d & 127) << 17) | src[i];
    }
}

// Pass C: per-bucket counting sort in LDS -> rowptr, col, inv_deg.
__global__ __launch_bounds__(256) void passC_build(const int* __restrict__ sorted_pk, const int* __restrict__ base,
                                                   int* __restrict__ rowptr, int* __restrict__ col,
                                                   float* __restrict__ invd, int n) {
    __shared__ int degl[128];
    __shared__ int s[256];
    __shared__ int curl[128];
    const int b = blockIdx.x, t = threadIdx.x;
    const int node0 = b << NB_SHIFT;
    const int nn = min(128, n - node0);
    const int e0 = base[b], e1 = base[b + 1];
    if (t < 128) degl[t] = 0;
    __syncthreads();
    for (int i = e0 + t; i < e1; i += 256)
        atomicAdd(&degl[sorted_pk[i] >> 17], 1);
    __syncthreads();
    int d = (t < 128) ? degl[t] : 0;
    s[t] = d; __syncthreads();
    for (int off = 1; off < 128; off <<= 1) {
        int x = (t >= off) ? s[t - off] : 0;
        __syncthreads();
        s[t] += x;
        __syncthreads();
    }
    if (t < 128) {
        int excl = s[t] - d;
        curl[t] = excl;
        if (t < nn) {
            rowptr[node0 + t] = e0 + excl;
            invd[node0 + t] = 1.0f / (float)(d > 0 ? d : 1);
        }
    }
    __syncthreads();
    for (int i = e0 + t; i < e1; i += 256) {
        int pk = sorted_pk[i];
        int p = atomicAdd(&curl[pk >> 17], 1);
        col[e0 + p] = pk & 0x1FFFF;
    }
}

// ---- type helpers ----
__device__ inline void store4(float* p, float x0, float x1, float x2, float x3) {
    *(float4*)p = make_float4(x0, x1, x2, x3);
}
__device__ inline void store4(__half* p, float x0, float x1, float x2, float x3) {
    union { __half h[4]; int2 i2; } u;
    u.h[0] = __float2half(x0); u.h[1] = __float2half(x1);
    u.h[2] = __float2half(x2); u.h[3] = __float2half(x3);
    *(int2*)p = u.i2;
}

// Gather-aggregate: one node per wave; lane = (edge_slot, feat_quad).
// Branchless pipelined loop (clamped col prefetch). 64 feats fp16.
// EPI: 0 = plain sum; 1 = relu(sum*inv_deg + bias).
template <int EPI>
__global__ __launch_bounds__(256) void agg_kernel(const __half* __restrict__ X, const int* __restrict__ col,
                                                  const int* __restrict__ rowptr,
                                                  const float* __restrict__ inv_deg,
                                                  const float* __restrict__ bias,
                                                  __half* __restrict__ out, int n) {
    constexpr int LPE = 16;          // lanes per edge
    constexpr int EPW = 4;           // edges per wave-issue
    const int node = blockIdx.x * 4 + (threadIdx.x >> 6);
    if (node >= n) return;
    const int lane = threadIdx.x & 63;
    const int eg = lane / LPE;
    const int fl = lane % LPE;
    const int s = rowptr[node], e = rowptr[node + 1];

    float ax = 0.f, ay = 0.f, az = 0.f, aw = 0.f;
    if (e > s) {
        int i = s + eg;
        const int nfull = (e - s) / EPW;
        int cc = col[min(i, e - 1)];
#pragma unroll 2
        for (int b = 0; b < nfull; ++b) {
            int cn = col[min(i + EPW, e - 1)];
            const __half* p = X + (size_t)cc * 64 + fl * 4;
            float2 f01 = __half22float2(*(const __half2*)p);
            float2 f23 = __half22float2(*(const __half2*)(p + 2));
            ax += f01.x; ay += f01.y; az += f23.x; aw += f23.y;
            cc = cn; i += EPW;
        }
        if (i < e) {
            const __half* p = X + (size_t)cc * 64 + fl * 4;
            float2 f01 = __half22float2(*(const __half2*)p);
            float2 f23 = __half22float2(*(const __half2*)(p + 2));
            ax += f01.x; ay += f01.y; az += f23.x; aw += f23.y;
        }
    }
#pragma unroll
    for (int m = LPE; m < 64; m <<= 1) {
        ax += __shfl_xor(ax, m);
        ay += __shfl_xor(ay, m);
        az += __shfl_xor(az, m);
        aw += __shfl_xor(aw, m);
    }
    if (eg == 0) {
        if (EPI != 0) {
            float sc = inv_deg[node];
            ax = fmaxf(ax * sc + bias[fl * 4 + 0], 0.f);
            ay = fmaxf(ay * sc + bias[fl * 4 + 1], 0.f);
            az = fmaxf(az * sc + bias[fl * 4 + 2], 0.f);
            aw = fmaxf(aw * sc + bias[fl * 4 + 3], 0.f);
        }
        store4(&out[(size_t)node * 64 + fl * 4], ax, ay, az, aw);
    }
}

// Final agg with fused matvec: out[node] = (agg(X2[node])/deg) @ W2 + b2.
__global__ __launch_bounds__(256) void agg_out_kernel(const __half* __restrict__ X2, const int* __restrict__ col,
                                                      const int* __restrict__ rowptr,
                                                      const float* __restrict__ inv_deg,
                                                      const float* __restrict__ W2, const float* __restrict__ b2,
                                                      float* __restrict__ out, int n) {
    __shared__ float W2s[64][33];
    __shared__ float vbuf[4][64];
    const int t = threadIdx.x;
#pragma unroll
    for (int l = 0; l < 8; ++l) {
        int o = t + l * 256;
        W2s[o >> 5][o & 31] = W2[o];
    }
    __syncthreads();

    const int node = blockIdx.x * 4 + (t >> 6);
    if (node >= n) return;
    const int wave = t >> 6, lane = t & 63;
    const int eg = lane >> 4, fl = lane & 15;   // LPE=16, EPW=4
    const int s = rowptr[node], e = rowptr[node + 1];

    float ax = 0.f, ay = 0.f, az = 0.f, aw = 0.f;
    if (e > s) {
        int i = s + eg;
        const int nfull = (e - s) / 4;
        int cc = col[min(i, e - 1)];
#pragma unroll 2
        for (int b = 0; b < nfull; ++b) {
            int cn = col[min(i + 4, e - 1)];
            const __half* p = X2 + (size_t)cc * 64 + fl * 4;
            float2 f01 = __half22float2(*(const __half2*)p);
            float2 f23 = __half22float2(*(const __half2*)(p + 2));
            ax += f01.x; ay += f01.y; az += f23.x; aw += f23.y;
            cc = cn; i += 4;
        }
        if (i < e) {
            const __half* p = X2 + (size_t)cc * 64 + fl * 4;
            float2 f01 = __half22float2(*(const __half2*)p);
            float2 f23 = __half22float2(*(const __half2*)(p + 2));
            ax += f01.x; ay += f01.y; az += f23.x; aw += f23.y;
        }
    }
#pragma unroll
    for (int m = 16; m < 64; m <<= 1) {
        ax += __shfl_xor(ax, m);
        ay += __shfl_xor(ay, m);
        az += __shfl_xor(az, m);
        aw += __shfl_xor(aw, m);
    }
    if (eg == 0) {
        float sc = inv_deg[node];
        vbuf[wave][fl * 4 + 0] = ax * sc;
        vbuf[wave][fl * 4 + 1] = ay * sc;
        vbuf[wave][fl * 4 + 2] = az * sc;
        vbuf[wave][fl * 4 + 3] = aw * sc;
    }
    const int c = lane & 31, kh = (lane >> 5) * 32;
    float sum = 0.f;
#pragma unroll 8
    for (int k = 0; k < 32; ++k)
        sum += vbuf[wave][kh + k] * W2s[kh + k][c];
    sum += __shfl_xor(sum, 32);
    if (lane < 32) out[(size_t)node * 32 + c] = sum + b2[c];
}

// Transpose+convert W0 [256][64] f32 -> W0t [64][256] fp16.
__global__ __launch_bounds__(256) void cvtW0t(const float* __restrict__ W0, __half* __restrict__ W0t) {
    int o = blockIdx.x * 256 + threadIdx.x;   // 16384 elems
    int c = o >> 8, k = o & 255;
    W0t[o] = __float2half(W0[k * 64 + c]);
}

// Transpose+convert W1 [64][64] f32 -> W1t [64][64] fp16.
__global__ __launch_bounds__(256) void cvtW1t(const float* __restrict__ W1, __half* __restrict__ W1t) {
    int o = blockIdx.x * 256 + threadIdx.x;   // 4096 elems
    int c = o >> 6, k = o & 63;
    W1t[o] = __float2half(W1[k * 64 + c]);
}

// Layer-0 GEMM on matrix cores: H[nrows x 64] = feat[nrows x 256] @ W0 (fp16 in, f32 acc).
__global__ __launch_bounds__(256) void gemm0_mfma(const float* __restrict__ A, const __half* __restrict__ W0t,
                                                  __half* __restrict__ out, int nrows) {
    constexpr int LDH = 280;   // 560B row stride: 16B aligned, 12-bank skew
    __shared__ _Float16 As[64][LDH];
    __shared__ _Float16 Bs[64][LDH];
    const int t = threadIdx.x;
    const int wave = t >> 6, lane = t & 63;
    const int row0 = blockIdx.x * 64;

#pragma unroll
    for (int l = 0; l < 16; ++l) {
        int fid = t + l * 256;
        int r = fid >> 6, c4 = fid & 63;
        int grow = row0 + r;
        int gr = grow < nrows ? grow : 0;
        float4 v = *(const float4*)&A[(size_t)gr * 256 + c4 * 4];
        _Float16* p = &As[r][c4 * 4];
        p[0] = (_Float16)v.x; p[1] = (_Float16)v.y;
        p[2] = (_Float16)v.z; p[3] = (_Float16)v.w;
    }
#pragma unroll
    for (int l = 0; l < 8; ++l) {
        int fid = t + l * 256;
        int r = fid >> 5, c8 = fid & 31;
        *(half8*)&Bs[r][c8 * 8] = *(const half8*)&W0t[r * 256 + c8 * 8];
    }
    __syncthreads();

    const int ar = wave * 16 + (lane & 15);
    const int kh = (lane >> 4) * 8;
    floatx4 acc0 = {0.f, 0.f, 0.f, 0.f}, acc1 = acc0, acc2 = acc0, acc3 = acc0;
#pragma unroll
    for (int ks = 0; ks < 8; ++ks) {
        const int k0 = ks * 32 + kh;
        half8 a = *(half8*)&As[ar][k0];
        half8 b0 = *(half8*)&Bs[ 0 + (lane & 15)][k0];
        half8 b1 = *(half8*)&Bs[16 + (lane & 15)][k0];
        half8 b2 = *(half8*)&Bs[32 + (lane & 15)][k0];
        half8 b3 = *(half8*)&Bs[48 + (lane & 15)][k0];
        acc0 = __builtin_amdgcn_mfma_f32_16x16x32_f16(a, b0, acc0, 0, 0, 0);
        acc1 = __builtin_amdgcn_mfma_f32_16x16x32_f16(a, b1, acc1, 0, 0, 0);
        acc2 = __builtin_amdgcn_mfma_f32_16x16x32_f16(a, b2, acc2, 0, 0, 0);
        acc3 = __builtin_amdgcn_mfma_f32_16x16x32_f16(a, b3, acc3, 0, 0, 0);
    }

    const int cc = lane & 15;
    const int rb = wave * 16 + (lane >> 4) * 4;
#pragma unroll
    for (int i = 0; i < 4; ++i) {
        int r = row0 + rb + i;
        if (r < nrows) {
            __half* po = &out[(size_t)r * 64];
            po[ 0 + cc] = __float2half(acc0[i]);
            po[16 + cc] = __float2half(acc1[i]);
            po[32 + cc] = __float2half(acc2[i]);
            po[48 + cc] = __float2half(acc3[i]);
        }
    }
}

// Layer-1 GEMM on matrix cores: X2 = relu((A2@W1)*inv_deg + b1), fp16 in/out.
__global__ __launch_bounds__(256) void gemm1_mfma(const __half* __restrict__ A2, const __half* __restrict__ W1t,
                                                  const float* __restrict__ b1, const float* __restrict__ inv_deg,
                                                  __half* __restrict__ out, int nrows) {
    constexpr int LDH = 88;    // 176B row stride: 16B aligned, 12-bank skew
    __shared__ _Float16 As[64][LDH];
    __shared__ _Float16 Bs[64][LDH];
    const int t = threadIdx.x;
    const int wave = t >> 6, lane = t & 63;
    const int row0 = blockIdx.x * 64;

    // Stage A2: 64x64 fp16, 512 half8 chunks, 2/thread.
#pragma unroll
    for (int l = 0; l < 2; ++l) {
        int fid = t + l * 256;
        int r = fid >> 3, c8 = fid & 7;
        int grow = row0 + r;
        int gr = grow < nrows ? grow : 0;
        *(half8*)&As[r][c8 * 8] = *(const half8*)&A2[(size_t)gr * 64 + c8 * 8];
    }
#pragma unroll
    for (int l = 0; l < 2; ++l) {
        int fid = t + l * 256;
        int r = fid >> 3, c8 = fid & 7;
        *(half8*)&Bs[r][c8 * 8] = *(const half8*)&W1t[r * 64 + c8 * 8];
    }
    __syncthreads();

    const int ar = wave * 16 + (lane & 15);
    const int kh = (lane >> 4) * 8;
    floatx4 acc0 = {0.f, 0.f, 0.f, 0.f}, acc1 = acc0, acc2 = acc0, acc3 = acc0;
#pragma unroll
    for (int ks = 0; ks < 2; ++ks) {
        const int k0 = ks * 32 + kh;
        half8 a = *(half8*)&As[ar][k0];
        half8 b0 = *(half8*)&Bs[ 0 + (lane & 15)][k0];
        half8 b1 = *(half8*)&Bs[16 + (lane & 15)][k0];
        half8 b2 = *(half8*)&Bs[32 + (lane & 15)][k0];
        half8 b3 = *(half8*)&Bs[48 + (lane & 15)][k0];
        acc0 = __builtin_amdgcn_mfma_f32_16x16x32_f16(a, b0, acc0, 0, 0, 0);
        acc1 = __builtin_amdgcn_mfma_f32_16x16x32_f16(a, b1, acc1, 0, 0, 0);
        acc2 = __builtin_amdgcn_mfma_f32_16x16x32_f16(a, b2, acc2, 0, 0, 0);
        acc3 = __builtin_amdgcn_mfma_f32_16x16x32_f16(a, b3, acc3, 0, 0, 0);
    }

    const int cc = lane & 15;
    const int rb = wave * 16 + (lane >> 4) * 4;
#pragma unroll
    for (int i = 0; i < 4; ++i) {
        int r = row0 + rb + i;
        if (r < nrows) {
            float sc = inv_deg[r];
            __half* po = &out[(size_t)r * 64];
            po[ 0 + cc] = __float2half(fmaxf(acc0[i] * sc + b1[ 0 + cc], 0.f));
            po[16 + cc] = __float2half(fmaxf(acc1[i] * sc + b1[16 + cc], 0.f));
            po[32 + cc] = __float2half(fmaxf(acc2[i] * sc + b1[32 + cc], 0.f));
            po[48 + cc] = __float2half(fmaxf(acc3[i] * sc + b1[48 + cc], 0.f));
        }
    }
}

extern "C" void kernel_launch(void* const* d_in, const int* in_sizes, int n_in,
                              void* d_out, int out_size, void* d_ws, size_t ws_size,
                              hipStream_t stream) {
    const float* feat = (const float*)d_in[0];
    const float* W0   = (const float*)d_in[1];
    const float* b0   = (const float*)d_in[2];
    const float* W1   = (const float*)d_in[3];
    const float* b1   = (const float*)d_in[4];
    const float* W2   = (const float*)d_in[5];
    const float* b2   = (const float*)d_in[6];
    const int*   src  = (const int*)d_in[7];
    const int*   dstv = (const int*)d_in[8];

    const int n = in_sizes[0] / 256;   // 100000
    const int e = in_sizes[7];         // 1600000

    const int nb   = (n + 127) >> NB_SHIFT;        // 782 buckets
    const int nblk = (e + EPB - 1) / EPB;          // 196 blocks

    // Workspace carve-up (256B aligned).
    char* base_p = (char*)d_ws;
    size_t off = 0;
    auto alloc = [&](size_t bytes) -> char* {
        char* p = base_p + off;
        off += (bytes + 255) & ~(size_t)255;
        return p;
    };
    float*  invd   = (float*)alloc((size_t)n * 4);
    int*    rowptr = (int*)alloc((size_t)(n + 1) * 4);
    int*    bbase  = (int*)alloc((size_t)(MAXNB + 1) * 4);
    int*    totals = (int*)alloc((size_t)MAXNB * 4);
    __half* W0t    = (__half*)alloc((size_t)256 * 64 * 2);
    __half* W1t    = (__half*)alloc((size_t)64 * 64 * 2);
    int*    col    = (int*)alloc((size_t)e * 4);          // C_T aliases col
    __half* bufH1  = (__half*)alloc((size_t)n * 64 * 2);  // H; later A2. sorted_pk aliases.
    __half* bufH2  = (__half*)alloc((size_t)n * 64 * 2);  // X1; later X2
    (void)ws_size;

    int* C_T       = col;           // nb*nblk ints (613KB) — dead before col is written
    int* sorted_pk = (int*)bufH1;   // e*4 B (6.4MB) — dead before gemm0 writes bufH1

    // --- CSR build (bucketed sort, no global atomics) ---
    passA_hist   <<<nblk, 256, 0, stream>>>(dstv, C_T, nb, nblk, e);
    bucket_prefix<<<nb,   256, 0, stream>>>(C_T, totals, nblk);
    scan_base    <<<1,    256, 0, stream>>>(totals, bbase, rowptr, nb, n, e);
    passB_scatter<<<nblk, 256, 0, stream>>>(src, dstv, C_T, bbase, sorted_pk, nb, nblk, e);
    passC_build  <<<nb,   256, 0, stream>>>(sorted_pk, bbase, rowptr, col, invd, n);
    cvtW0t       <<<64,   256, 0, stream>>>(W0, W0t);
    cvtW1t       <<<16,   256, 0, stream>>>(W1, W1t);

    const int gemm_blocks = (n + 63) / 64;
    const int agg_blocks  = (n + 3) / 4;   // one wave per node, 4 waves/block

    // --- Layer 0: H = feat@W0 (MFMA) ; X1 = relu(agg(H)*inv + b0) ---
    gemm0_mfma<<<gemm_blocks, 256, 0, stream>>>(feat, W0t, bufH1, n);
    agg_kernel<1><<<agg_blocks, 256, 0, stream>>>(bufH1, col, rowptr, invd, b0, bufH2, n);

    // --- Layer 1: A2 = agg(X1) ; X2 = relu((A2@W1)*inv + b1) (MFMA) ---
    agg_kernel<0><<<agg_blocks, 256, 0, stream>>>(bufH2, col, rowptr, nullptr, nullptr, bufH1, n);
    gemm1_mfma<<<gemm_blocks, 256, 0, stream>>>(bufH1, W1t, b1, invd, bufH2, n);

    // --- Layer 2 (commuted): out = (agg(X2)/deg)@W2 + b2 ---
    agg_out_kernel<<<agg_blocks, 256, 0, stream>>>(bufH2, col, rowptr, invd, W2, b2, (float*)d_out, n);
}

// Round 9
// 203.797 us; speedup vs baseline: 1.1436x; 1.1097x over previous
//
#include <hip/hip_runtime.h>
#include <hip/hip_bf16.h>
#include <hip/hip_fp16.h>

// GCN: 3 layers over fixed graph (N=100000 nodes, E=1600000 edges).
// CSR build via bucketed sort (128-node buckets, EPB=2048 for machine fill).
// Gather aggs: branchless pipelined, ~23cyc/edge MSHR floor; footprint
// minimized (final agg gathers 32f H2, 6.4MB -> best L2 hit rate).
// gemm0 and fused gemm12 on matrix cores (mfma 16x16x32 f16, f32 accum).

constexpr int NB_SHIFT = 7;          // 128 nodes per bucket
constexpr int EPB = 2048;            // edges per block in pass A/B (782 blocks)
constexpr int MAXNB = 800;           // >= ceil(100000/128)=782

using half8   = __attribute__((ext_vector_type(8))) _Float16;
using floatx4 = __attribute__((ext_vector_type(4))) float;

// Pass A: per-block LDS histogram over buckets -> C_T[bucket][block] counts.
__global__ __launch_bounds__(256) void passA_hist(const int* __restrict__ dst, int* __restrict__ C_T,
                                                  int nb, int nblk, int n_edges) {
    __shared__ int h[MAXNB];
    for (int i = threadIdx.x; i < nb; i += 256) h[i] = 0;
    __syncthreads();
    const int e0 = blockIdx.x * EPB;
    const int e1 = min(e0 + EPB, n_edges);
    for (int i = e0 + threadIdx.x; i < e1; i += 256)
        atomicAdd(&h[dst[i] >> NB_SHIFT], 1);
    __syncthreads();
    for (int i = threadIdx.x; i < nb; i += 256)
        C_T[i * nblk + blockIdx.x] = h[i];
}

// Per-bucket exclusive scan across blocks (in place, nblk <= 1024); totals out.
__global__ __launch_bounds__(256) void bucket_prefix(int* __restrict__ C_T, int* __restrict__ totals,
                                                     int nblk) {
    __shared__ int s[256];
    const int b = blockIdx.x, t = threadIdx.x;
    int v[4]; int ts = 0;
#pragma unroll
    for (int j = 0; j < 4; ++j) { int i = t * 4 + j; v[j] = (i < nblk) ? C_T[b * nblk + i] : 0; ts += v[j]; }
    s[t] = ts; __syncthreads();
    for (int off = 1; off < 256; off <<= 1) {
        int x = (t >= off) ? s[t - off] : 0;
        __syncthreads();
        s[t] += x;
        __syncthreads();
    }
    int run = s[t] - ts;
#pragma unroll
    for (int j = 0; j < 4; ++j) { int i = t * 4 + j; if (i < nblk) C_T[b * nblk + i] = run; run += v[j]; }
    if (t == 255) totals[b] = s[255];
}

// Exclusive scan of bucket totals -> base[nb+1]; also rowptr[n]=E.
__global__ __launch_bounds__(256) void scan_base(const int* __restrict__ totals, int* __restrict__ base_out,
                                                 int* __restrict__ rowptr, int nb, int n, int n_edges) {
    __shared__ int s[256];
    const int t = threadIdx.x;
    int v[4]; int ts = 0;
#pragma unroll
    for (int j = 0; j < 4; ++j) { int i = t * 4 + j; v[j] = (i < nb) ? totals[i] : 0; ts += v[j]; }
    s[t] = ts; __syncthreads();
    for (int off = 1; off < 256; off <<= 1) {
        int x = (t >= off) ? s[t - off] : 0;
        __syncthreads();
        s[t] += x;
        __syncthreads();
    }
    int run = s[t] - ts;
#pragma unroll
    for (int j = 0; j < 4; ++j) { int i = t * 4 + j; if (i < nb) base_out[i] = run; run += v[j]; }
    if (t == 255) base_out[nb] = s[255];
    if (t == 0) rowptr[n] = n_edges;
}

// Pass B: scatter packed (ldst<<17)|src into bucket order using LDS cursors.
__global__ __launch_bounds__(256) void passB_scatter(const int* __restrict__ src, const int* __restrict__ dst,
                                                     const int* __restrict__ C_T, const int* __restrict__ base,
                                                     int* __restrict__ sorted_pk, int nb, int nblk, int n_edges) {
    __shared__ int cur[MAXNB];
    const int blk = blockIdx.x;
    for (int i = threadIdx.x; i < nb; i += 256) cur[i] = base[i] + C_T[i * nblk + blk];
    __syncthreads();
    const int e0 = blk * EPB;
    const int e1 = min(e0 + EPB, n_edges);
    for (int i = e0 + threadIdx.x; i < e1; i += 256) {
        int d = dst[i];
        int p = atomicAdd(&cur[d >> NB_SHIFT], 1);
        sorted_pk[p] = ((d & 127) << 17) | src[i];
    }
}

// Pass C: per-bucket counting sort in LDS -> rowptr, col, inv_deg.
__global__ __launch_bounds__(256) void passC_build(const int* __restrict__ sorted_pk, const int* __restrict__ base,
                                                   int* __restrict__ rowptr, int* __restrict__ col,
                                                   float* __restrict__ invd, int n) {
    __shared__ int degl[128];
    __shared__ int s[256];
    __shared__ int curl[128];
    const int b = blockIdx.x, t = threadIdx.x;
    const int node0 = b << NB_SHIFT;
    const int nn = min(128, n - node0);
    const int e0 = base[b], e1 = base[b + 1];
    if (t < 128) degl[t] = 0;
    __syncthreads();
    for (int i = e0 + t; i < e1; i += 256)
        atomicAdd(&degl[sorted_pk[i] >> 17], 1);
    __syncthreads();
    int d = (t < 128) ? degl[t] : 0;
    s[t] = d; __syncthreads();
    for (int off = 1; off < 128; off <<= 1) {
        int x = (t >= off) ? s[t - off] : 0;
        __syncthreads();
        s[t] += x;
        __syncthreads();
    }
    if (t < 128) {
        int excl = s[t] - d;
        curl[t] = excl;
        if (t < nn) {
            rowptr[node0 + t] = e0 + excl;
            invd[node0 + t] = 1.0f / (float)(d > 0 ? d : 1);
        }
    }
    __syncthreads();
    for (int i = e0 + t; i < e1; i += 256) {
        int pk = sorted_pk[i];
        int p = atomicAdd(&curl[pk >> 17], 1);
        col[e0 + p] = pk & 0x1FFFF;
    }
}

// ---- type helpers ----
__device__ inline void store4(float* p, float x0, float x1, float x2, float x3) {
    *(float4*)p = make_float4(x0, x1, x2, x3);
}
__device__ inline void store4(__half* p, float x0, float x1, float x2, float x3) {
    union { __half h[4]; int2 i2; } u;
    u.h[0] = __float2half(x0); u.h[1] = __float2half(x1);
    u.h[2] = __float2half(x2); u.h[3] = __float2half(x3);
    *(int2*)p = u.i2;
}

// Gather-aggregate: one node per wave; lane = (edge_slot, feat_quad).
// Branchless pipelined loop (clamped col prefetch).
// EPI: 0 = plain sum; 1 = relu(sum*inv_deg + bias); 2 = sum*inv_deg + bias.
template <int FEATS, int EPI, typename OutT>
__global__ __launch_bounds__(256) void agg_kernel(const __half* __restrict__ X, const int* __restrict__ col,
                                                  const int* __restrict__ rowptr,
                                                  const float* __restrict__ inv_deg,
                                                  const float* __restrict__ bias,
                                                  OutT* __restrict__ out, int n) {
    constexpr int LPE = FEATS / 4;   // lanes per edge (16 or 8)
    constexpr int EPW = 64 / LPE;    // edges per wave-issue (4 or 8)
    const int node = blockIdx.x * 4 + (threadIdx.x >> 6);
    if (node >= n) return;
    const int lane = threadIdx.x & 63;
    const int eg = lane / LPE;
    const int fl = lane % LPE;
    const int s = rowptr[node], e = rowptr[node + 1];

    float ax = 0.f, ay = 0.f, az = 0.f, aw = 0.f;
    if (e > s) {
        int i = s + eg;
        const int nfull = (e - s) / EPW;
        int cc = col[min(i, e - 1)];
#pragma unroll 2
        for (int b = 0; b < nfull; ++b) {
            int cn = col[min(i + EPW, e - 1)];
            const __half* p = X + (size_t)cc * FEATS + fl * 4;
            float2 f01 = __half22float2(*(const __half2*)p);
            float2 f23 = __half22float2(*(const __half2*)(p + 2));
            ax += f01.x; ay += f01.y; az += f23.x; aw += f23.y;
            cc = cn; i += EPW;
        }
        if (i < e) {
            const __half* p = X + (size_t)cc * FEATS + fl * 4;
            float2 f01 = __half22float2(*(const __half2*)p);
            float2 f23 = __half22float2(*(const __half2*)(p + 2));
            ax += f01.x; ay += f01.y; az += f23.x; aw += f23.y;
        }
    }
#pragma unroll
    for (int m = LPE; m < 64; m <<= 1) {
        ax += __shfl_xor(ax, m);
        ay += __shfl_xor(ay, m);
        az += __shfl_xor(az, m);
        aw += __shfl_xor(aw, m);
    }
    if (eg == 0) {
        if (EPI != 0) {
            float sc = inv_deg[node];
            ax = ax * sc + bias[fl * 4 + 0];
            ay = ay * sc + bias[fl * 4 + 1];
            az = az * sc + bias[fl * 4 + 2];
            aw = aw * sc + bias[fl * 4 + 3];
            if (EPI == 1) {
                ax = fmaxf(ax, 0.f); ay = fmaxf(ay, 0.f);
                az = fmaxf(az, 0.f); aw = fmaxf(aw, 0.f);
            }
        }
        store4(&out[(size_t)node * FEATS + fl * 4], ax, ay, az, aw);
    }
}

// Transpose+convert all weights to fp16: W0t[64][256], W1t[64][64], W2t[32][64].
__global__ __launch_bounds__(256) void cvt_weights(const float* __restrict__ W0, const float* __restrict__ W1,
                                                   const float* __restrict__ W2,
                                                   __half* __restrict__ W0t, __half* __restrict__ W1t,
                                                   __half* __restrict__ W2t) {
    const int b = blockIdx.x, t = threadIdx.x;
    if (b < 64) {        // W0 [256][64] -> W0t [64][256]
        int o = b * 256 + t;
        W0t[o] = __float2half(W0[(o & 255) * 64 + (o >> 8)]);
    } else if (b < 80) { // W1 [64][64] -> W1t [64][64]
        int o = (b - 64) * 256 + t;
        W1t[o] = __float2half(W1[(o & 63) * 64 + (o >> 6)]);
    } else {             // W2 [64][32] -> W2t [32][64]
        int o = (b - 80) * 256 + t;
        W2t[o] = __float2half(W2[(o & 63) * 32 + (o >> 6)]);
    }
}

// Layer-0 GEMM on matrix cores: H[nrows x 64] = feat[nrows x 256] @ W0 (fp16 in, f32 acc).
__global__ __launch_bounds__(256) void gemm0_mfma(const float* __restrict__ A, const __half* __restrict__ W0t,
                                                  __half* __restrict__ out, int nrows) {
    constexpr int LDH = 280;   // 560B row stride: 16B aligned, bank-skewed
    __shared__ _Float16 As[64][LDH];
    __shared__ _Float16 Bs[64][LDH];
    const int t = threadIdx.x;
    const int wave = t >> 6, lane = t & 63;
    const int row0 = blockIdx.x * 64;

#pragma unroll
    for (int l = 0; l < 16; ++l) {
        int fid = t + l * 256;
        int r = fid >> 6, c4 = fid & 63;
        int grow = row0 + r;
        int gr = grow < nrows ? grow : 0;
        float4 v = *(const float4*)&A[(size_t)gr * 256 + c4 * 4];
        _Float16* p = &As[r][c4 * 4];
        p[0] = (_Float16)v.x; p[1] = (_Float16)v.y;
        p[2] = (_Float16)v.z; p[3] = (_Float16)v.w;
    }
#pragma unroll
    for (int l = 0; l < 8; ++l) {
        int fid = t + l * 256;
        int r = fid >> 5, c8 = fid & 31;
        *(half8*)&Bs[r][c8 * 8] = *(const half8*)&W0t[r * 256 + c8 * 8];
    }
    __syncthreads();

    const int ar = wave * 16 + (lane & 15);
    const int kh = (lane >> 4) * 8;
    floatx4 acc0 = {0.f, 0.f, 0.f, 0.f}, acc1 = acc0, acc2 = acc0, acc3 = acc0;
#pragma unroll
    for (int ks = 0; ks < 8; ++ks) {
        const int k0 = ks * 32 + kh;
        half8 a = *(half8*)&As[ar][k0];
        half8 b0 = *(half8*)&Bs[ 0 + (lane & 15)][k0];
        half8 b1 = *(half8*)&Bs[16 + (lane & 15)][k0];
        half8 b2 = *(half8*)&Bs[32 + (lane & 15)][k0];
        half8 b3 = *(half8*)&Bs[48 + (lane & 15)][k0];
        acc0 = __builtin_amdgcn_mfma_f32_16x16x32_f16(a, b0, acc0, 0, 0, 0);
        acc1 = __builtin_amdgcn_mfma_f32_16x16x32_f16(a, b1, acc1, 0, 0, 0);
        acc2 = __builtin_amdgcn_mfma_f32_16x16x32_f16(a, b2, acc2, 0, 0, 0);
        acc3 = __builtin_amdgcn_mfma_f32_16x16x32_f16(a, b3, acc3, 0, 0, 0);
    }

    const int cc = lane & 15;
    const int rb = wave * 16 + (lane >> 4) * 4;
#pragma unroll
    for (int i = 0; i < 4; ++i) {
        int r = row0 + rb + i;
        if (r < nrows) {
            __half* po = &out[(size_t)r * 64];
            po[ 0 + cc] = __float2half(acc0[i]);
            po[16 + cc] = __float2half(acc1[i]);
            po[32 + cc] = __float2half(acc2[i]);
            po[48 + cc] = __float2half(acc3[i]);
        }
    }
}

// Fused layers 1+2 GEMM, full MFMA: X2 = relu((A2@W1)*inv+b1) (LDS, fp16);
// H2 = X2@W2 -> out (fp16, 32 cols).
__global__ __launch_bounds__(256) void gemm12_mfma(const __half* __restrict__ A2, const __half* __restrict__ W1t,
                                                   const float* __restrict__ b1, const __half* __restrict__ W2t,
                                                   const float* __restrict__ inv_deg,
                                                   __half* __restrict__ out, int nrows) {
    constexpr int LDH = 72;    // 144B row stride: 16B aligned, bank-skewed
    __shared__ _Float16 As [64][LDH];
    __shared__ _Float16 B1s[64][LDH];
    __shared__ _Float16 B2s[32][LDH];
    __shared__ _Float16 X2s[64][LDH];
    const int t = threadIdx.x;
    const int wave = t >> 6, lane = t & 63;
    const int row0 = blockIdx.x * 64;

    // Stage A2 (64x64 fp16, 512 half8 chunks, 2/thread) + W1t + W2t.
#pragma unroll
    for (int l = 0; l < 2; ++l) {
        int fid = t + l * 256;
        int r = fid >> 3, c8 = fid & 7;
        int grow = row0 + r;
        int gr = grow < nrows ? grow : 0;
        *(half8*)&As[r][c8 * 8] = *(const half8*)&A2[(size_t)gr * 64 + c8 * 8];
    }
#pragma unroll
    for (int l = 0; l < 2; ++l) {
        int fid = t + l * 256;
        int r = fid >> 3, c8 = fid & 7;
        *(half8*)&B1s[r][c8 * 8] = *(const half8*)&W1t[r * 64 + c8 * 8];
    }
    {
        int r = t >> 3, c8 = t & 7;
        *(half8*)&B2s[r][c8 * 8] = *(const half8*)&W2t[r * 64 + c8 * 8];
    }
    __syncthreads();

    const int ar = wave * 16 + (lane & 15);
    const int kh = (lane >> 4) * 8;
    const int cc = lane & 15;
    const int rb = wave * 16 + (lane >> 4) * 4;

    // Phase 1: acc = A2 @ W1 (K=64)
    floatx4 acc0 = {0.f, 0.f, 0.f, 0.f}, acc1 = acc0, acc2 = acc0, acc3 = acc0;
#pragma unroll
    for (int ks = 0; ks < 2; ++ks) {
        const int k0 = ks * 32 + kh;
        half8 a = *(half8*)&As[ar][k0];
        half8 b0 = *(half8*)&B1s[ 0 + (lane & 15)][k0];
        half8 b1v = *(half8*)&B1s[16 + (lane & 15)][k0];
        half8 b2v = *(half8*)&B1s[32 + (lane & 15)][k0];
        half8 b3v = *(half8*)&B1s[48 + (lane & 15)][k0];
        acc0 = __builtin_amdgcn_mfma_f32_16x16x32_f16(a, b0, acc0, 0, 0, 0);
        acc1 = __builtin_amdgcn_mfma_f32_16x16x32_f16(a, b1v, acc1, 0, 0, 0);
        acc2 = __builtin_amdgcn_mfma_f32_16x16x32_f16(a, b2v, acc2, 0, 0, 0);
        acc3 = __builtin_amdgcn_mfma_f32_16x16x32_f16(a, b3v, acc3, 0, 0, 0);
    }

    // Epilogue 1: X2 = relu(acc*inv + b1) -> LDS fp16 (C/D layout: col=cc, row=rb+i).
#pragma unroll
    for (int i = 0; i < 4; ++i) {
        int r = row0 + rb + i;
        float sc = (r < nrows) ? inv_deg[r] : 0.f;
        X2s[rb + i][ 0 + cc] = (_Float16)fmaxf(acc0[i] * sc + b1[ 0 + cc], 0.f);
        X2s[rb + i][16 + cc] = (_Float16)fmaxf(acc1[i] * sc + b1[16 + cc], 0.f);
        X2s[rb + i][32 + cc] = (_Float16)fmaxf(acc2[i] * sc + b1[32 + cc], 0.f);
        X2s[rb + i][48 + cc] = (_Float16)fmaxf(acc3[i] * sc + b1[48 + cc], 0.f);
    }
    __syncthreads();

    // Phase 2: H2 = X2 @ W2 (64x64 @ 64x32)
    floatx4 acc4 = {0.f, 0.f, 0.f, 0.f}, acc5 = acc4;
#pragma unroll
    for (int ks = 0; ks < 2; ++ks) {
        const int k0 = ks * 32 + kh;
        half8 a = *(half8*)&X2s[ar][k0];
        half8 c0 = *(half8*)&B2s[ 0 + (lane & 15)][k0];
        half8 c1 = *(half8*)&B2s[16 + (lane & 15)][k0];
        acc4 = __builtin_amdgcn_mfma_f32_16x16x32_f16(a, c0, acc4, 0, 0, 0);
        acc5 = __builtin_amdgcn_mfma_f32_16x16x32_f16(a, c1, acc5, 0, 0, 0);
    }

#pragma unroll
    for (int i = 0; i < 4; ++i) {
        int r = row0 + rb + i;
        if (r < nrows) {
            __half* po = &out[(size_t)r * 32];
            po[ 0 + cc] = __float2half(acc4[i]);
            po[16 + cc] = __float2half(acc5[i]);
        }
    }
}

extern "C" void kernel_launch(void* const* d_in, const int* in_sizes, int n_in,
                              void* d_out, int out_size, void* d_ws, size_t ws_size,
                              hipStream_t stream) {
    const float* feat = (const float*)d_in[0];
    const float* W0   = (const float*)d_in[1];
    const float* b0   = (const float*)d_in[2];
    const float* W1   = (const float*)d_in[3];
    const float* b1   = (const float*)d_in[4];
    const float* W2   = (const float*)d_in[5];
    const float* b2   = (const float*)d_in[6];
    const int*   src  = (const int*)d_in[7];
    const int*   dstv = (const int*)d_in[8];

    const int n = in_sizes[0] / 256;   // 100000
    const int e = in_sizes[7];         // 1600000

    const int nb   = (n + 127) >> NB_SHIFT;        // 782 buckets
    const int nblk = (e + EPB - 1) / EPB;          // 782 blocks

    // Workspace carve-up (256B aligned).
    char* base_p = (char*)d_ws;
    size_t off = 0;
    auto alloc = [&](size_t bytes) -> char* {
        char* p = base_p + off;
        off += (bytes + 255) & ~(size_t)255;
        return p;
    };
    float*  invd   = (float*)alloc((size_t)n * 4);
    int*    rowptr = (int*)alloc((size_t)(n + 1) * 4);
    int*    bbase  = (int*)alloc((size_t)(MAXNB + 1) * 4);
    int*    totals = (int*)alloc((size_t)MAXNB * 4);
    __half* W0t    = (__half*)alloc((size_t)256 * 64 * 2);
    __half* W1t    = (__half*)alloc((size_t)64 * 64 * 2);
    __half* W2t    = (__half*)alloc((size_t)32 * 64 * 2);
    int*    col    = (int*)alloc((size_t)e * 4);          // C_T aliases col (nb*nblk=2.45MB < 6.4MB)
    __half* bufH1  = (__half*)alloc((size_t)n * 64 * 2);  // H; later A2. sorted_pk aliases.
    __half* bufH2  = (__half*)alloc((size_t)n * 64 * 2);  // X1; later H2 (32f)
    (void)ws_size;

    int* C_T       = col;           // dead before col is written
    int* sorted_pk = (int*)bufH1;   // e*4 B (6.4MB) — dead before gemm0 writes bufH1

    // --- CSR build (bucketed sort, no global atomics) ---
    passA_hist   <<<nblk, 256, 0, stream>>>(dstv, C_T, nb, nblk, e);
    bucket_prefix<<<nb,   256, 0, stream>>>(C_T, totals, nblk);
    scan_base    <<<1,    256, 0, stream>>>(totals, bbase, rowptr, nb, n, e);
    passB_scatter<<<nblk, 256, 0, stream>>>(src, dstv, C_T, bbase, sorted_pk, nb, nblk, e);
    passC_build  <<<nb,   256, 0, stream>>>(sorted_pk, bbase, rowptr, col, invd, n);
    cvt_weights  <<<88,   256, 0, stream>>>(W0, W1, W2, W0t, W1t, W2t);

    const int gemm_blocks = (n + 63) / 64;
    const int agg_blocks  = (n + 3) / 4;   // one wave per node, 4 waves/block

    // --- Layer 0: H = feat@W0 (MFMA) ; X1 = relu(agg(H)*inv + b0) ---
    gemm0_mfma<<<gemm_blocks, 256, 0, stream>>>(feat, W0t, bufH1, n);
    agg_kernel<64, 1, __half><<<agg_blocks, 256, 0, stream>>>(bufH1, col, rowptr, invd, b0, bufH2, n);

    // --- Layer 1: A2 = agg(X1) ; fused MFMA: X2 = relu((A2@W1)*inv+b1); H2 = X2@W2 ---
    agg_kernel<64, 0, __half><<<agg_blocks, 256, 0, stream>>>(bufH2, col, rowptr, nullptr, nullptr, bufH1, n);
    gemm12_mfma<<<gemm_blocks, 256, 0, stream>>>(bufH1, W1t, b1, W2t, invd, bufH2, n);

    // --- Layer 2: out = agg(H2)*inv + b2 (32f gather over 6.4MB) ---
    agg_kernel<32, 2, float><<<agg_blocks, 256, 0, stream>>>(bufH2, col, rowptr, invd, b2, (float*)d_out, n);
}

// Round 10
// 190.385 us; speedup vs baseline: 1.2242x; 1.0704x over previous
//
#include <hip/hip_runtime.h>
#include <hip/hip_bf16.h>
#include <hip/hip_fp16.h>

// GCN: 3 layers over fixed graph (N=100000 nodes, E=1600000 edges).
// CSR build via bucketed sort: passA (histogram) at EPB=2048 for machine
// fill, passB (scatter) at 8192-edge ranges for write-run locality; both
// read edges as int4. Gather aggs at the measured ~23cyc/random-line
// floor; footprint-minimized fp16 buffers. GEMMs on matrix cores.

constexpr int NB_SHIFT = 7;          // 128 nodes per bucket
constexpr int EPB_A = 2048;          // passA edges per block (782 blocks)
constexpr int EPB_B = 8192;          // passB edges per block (196 blocks)
constexpr int MAXNB = 800;           // >= ceil(100000/128)=782

using half8   = __attribute__((ext_vector_type(8))) _Float16;
using floatx4 = __attribute__((ext_vector_type(4))) float;

// Pass A: per-block LDS histogram over buckets -> C_T[bucket][blockA] counts.
// Assumes EPB_A and n_edges are multiples of 4 (int4 reads).
__global__ __launch_bounds__(256) void passA_hist(const int* __restrict__ dst, int* __restrict__ C_T,
                                                  int nb, int nblkA, int n_edges) {
    __shared__ int h[MAXNB];
    for (int i = threadIdx.x; i < nb; i += 256) h[i] = 0;
    __syncthreads();
    const int e0 = blockIdx.x * EPB_A;
    const int e1 = min(e0 + EPB_A, n_edges);
    for (int i4 = e0 + threadIdx.x * 4; i4 < e1; i4 += 1024) {
        int4 d4 = *(const int4*)&dst[i4];
        atomicAdd(&h[d4.x >> NB_SHIFT], 1);
        atomicAdd(&h[d4.y >> NB_SHIFT], 1);
        atomicAdd(&h[d4.z >> NB_SHIFT], 1);
        atomicAdd(&h[d4.w >> NB_SHIFT], 1);
    }
    __syncthreads();
    for (int i = threadIdx.x; i < nb; i += 256)
        C_T[i * nblkA + blockIdx.x] = h[i];
}

// Per-bucket exclusive scan across blockA columns (in place, nblkA <= 1024); totals out.
__global__ __launch_bounds__(256) void bucket_prefix(int* __restrict__ C_T, int* __restrict__ totals,
                                                     int nblkA) {
    __shared__ int s[256];
    const int b = blockIdx.x, t = threadIdx.x;
    int v[4]; int ts = 0;
#pragma unroll
    for (int j = 0; j < 4; ++j) { int i = t * 4 + j; v[j] = (i < nblkA) ? C_T[b * nblkA + i] : 0; ts += v[j]; }
    s[t] = ts; __syncthreads();
    for (int off = 1; off < 256; off <<= 1) {
        int x = (t >= off) ? s[t - off] : 0;
        __syncthreads();
        s[t] += x;
        __syncthreads();
    }
    int run = s[t] - ts;
#pragma unroll
    for (int j = 0; j < 4; ++j) { int i = t * 4 + j; if (i < nblkA) C_T[b * nblkA + i] = run; run += v[j]; }
    if (t == 255) totals[b] = s[255];
}

// Block 0: exclusive scan of bucket totals -> base[nb+1], rowptr[n]=E.
// Blocks 1..88: transpose+convert weights to fp16 (W0t[64][256], W1t[64][64], W2t[32][64]).
__global__ __launch_bounds__(256) void scan_cvt(const int* __restrict__ totals, int* __restrict__ base_out,
                                                int* __restrict__ rowptr, int nb, int n, int n_edges,
                                                const float* __restrict__ W0, const float* __restrict__ W1,
                                                const float* __restrict__ W2,
                                                __half* __restrict__ W0t, __half* __restrict__ W1t,
                                                __half* __restrict__ W2t) {
    const int t = threadIdx.x;
    if (blockIdx.x == 0) {
        __shared__ int s[256];
        int v[4]; int ts = 0;
#pragma unroll
        for (int j = 0; j < 4; ++j) { int i = t * 4 + j; v[j] = (i < nb) ? totals[i] : 0; ts += v[j]; }
        s[t] = ts; __syncthreads();
        for (int off = 1; off < 256; off <<= 1) {
            int x = (t >= off) ? s[t - off] : 0;
            __syncthreads();
            s[t] += x;
            __syncthreads();
        }
        int run = s[t] - ts;
#pragma unroll
        for (int j = 0; j < 4; ++j) { int i = t * 4 + j; if (i < nb) base_out[i] = run; run += v[j]; }
        if (t == 255) base_out[nb] = s[255];
        if (t == 0) rowptr[n] = n_edges;
    } else {
        const int b = blockIdx.x - 1;
        if (b < 64) {        // W0 [256][64] -> W0t [64][256]
            int o = b * 256 + t;
            W0t[o] = __float2half(W0[(o & 255) * 64 + (o >> 8)]);
        } else if (b < 80) { // W1 [64][64] -> W1t [64][64]
            int o = (b - 64) * 256 + t;
            W1t[o] = __float2half(W1[(o & 63) * 64 + (o >> 6)]);
        } else {             // W2 [64][32] -> W2t [32][64]
            int o = (b - 80) * 256 + t;
            W2t[o] = __float2half(W2[(o & 63) * 32 + (o >> 6)]);
        }
    }
}

// Pass B: scatter packed (ldst<<17)|src into bucket order using LDS cursors.
// Covers EPB_B edges = EPB_B/EPB_A passA sub-blocks; cursor starts at the
// exclusive prefix of its first sub-block column.
__global__ __launch_bounds__(256) void passB_scatter(const int* __restrict__ src, const int* __restrict__ dst,
                                                     const int* __restrict__ C_T, const int* __restrict__ base,
                                                     int* __restrict__ sorted_pk, int nb, int nblkA, int n_edges) {
    __shared__ int cur[MAXNB];
    const int blk = blockIdx.x;
    const int colA = blk * (EPB_B / EPB_A);
    for (int i = threadIdx.x; i < nb; i += 256) cur[i] = base[i] + C_T[i * nblkA + colA];
    __syncthreads();
    const int e0 = blk * EPB_B;
    const int e1 = min(e0 + EPB_B, n_edges);
    for (int i4 = e0 + threadIdx.x * 4; i4 < e1; i4 += 1024) {
        int4 s4 = *(const int4*)&src[i4];
        int4 d4 = *(const int4*)&dst[i4];
        int p0 = atomicAdd(&cur[d4.x >> NB_SHIFT], 1);
        sorted_pk[p0] = ((d4.x & 127) << 17) | s4.x;
        int p1 = atomicAdd(&cur[d4.y >> NB_SHIFT], 1);
        sorted_pk[p1] = ((d4.y & 127) << 17) | s4.y;
        int p2 = atomicAdd(&cur[d4.z >> NB_SHIFT], 1);
        sorted_pk[p2] = ((d4.z & 127) << 17) | s4.z;
        int p3 = atomicAdd(&cur[d4.w >> NB_SHIFT], 1);
        sorted_pk[p3] = ((d4.w & 127) << 17) | s4.w;
    }
}

// Pass C: per-bucket counting sort in LDS -> rowptr, col, inv_deg.
__global__ __launch_bounds__(256) void passC_build(const int* __restrict__ sorted_pk, const int* __restrict__ base,
                                                   int* __restrict__ rowptr, int* __restrict__ col,
                                                   float* __restrict__ invd, int n) {
    __shared__ int degl[128];
    __shared__ int s[256];
    __shared__ int curl[128];
    const int b = blockIdx.x, t = threadIdx.x;
    const int node0 = b << NB_SHIFT;
    const int nn = min(128, n - node0);
    const int e0 = base[b], e1 = base[b + 1];
    if (t < 128) degl[t] = 0;
    __syncthreads();
    for (int i = e0 + t; i < e1; i += 256)
        atomicAdd(&degl[sorted_pk[i] >> 17], 1);
    __syncthreads();
    int d = (t < 128) ? degl[t] : 0;
    s[t] = d; __syncthreads();
    for (int off = 1; off < 128; off <<= 1) {
        int x = (t >= off) ? s[t - off] : 0;
        __syncthreads();
        s[t] += x;
        __syncthreads();
    }
    if (t < 128) {
        int excl = s[t] - d;
        curl[t] = excl;
        if (t < nn) {
            rowptr[node0 + t] = e0 + excl;
            invd[node0 + t] = 1.0f / (float)(d > 0 ? d : 1);
        }
    }
    __syncthreads();
    for (int i = e0 + t; i < e1; i += 256) {
        int pk = sorted_pk[i];
        int p = atomicAdd(&curl[pk >> 17], 1);
        col[e0 + p] = pk & 0x1FFFF;
    }
}

// ---- type helpers ----
__device__ inline void store4(float* p, float x0, float x1, float x2, float x3) {
    *(float4*)p = make_float4(x0, x1, x2, x3);
}
__device__ inline void store4(__half* p, float x0, float x1, float x2, float x3) {
    union { __half h[4]; int2 i2; } u;
    u.h[0] = __float2half(x0); u.h[1] = __float2half(x1);
    u.h[2] = __float2half(x2); u.h[3] = __float2half(x3);
    *(int2*)p = u.i2;
}

// Gather-aggregate: one node per wave; lane = (edge_slot, feat_quad).
// Branchless pipelined loop (clamped col prefetch).
// EPI: 0 = plain sum; 1 = relu(sum*inv_deg + bias); 2 = sum*inv_deg + bias.
template <int FEATS, int EPI, typename OutT>
__global__ __launch_bounds__(256) void agg_kernel(const __half* __restrict__ X, const int* __restrict__ col,
                                                  const int* __restrict__ rowptr,
                                                  const float* __restrict__ inv_deg,
                                                  const float* __restrict__ bias,
                                                  OutT* __restrict__ out, int n) {
    constexpr int LPE = FEATS / 4;   // lanes per edge (16 or 8)
    constexpr int EPW = 64 / LPE;    // edges per wave-issue (4 or 8)
    const int node = blockIdx.x * 4 + (threadIdx.x >> 6);
    if (node >= n) return;
    const int lane = threadIdx.x & 63;
    const int eg = lane / LPE;
    const int fl = lane % LPE;
    const int s = rowptr[node], e = rowptr[node + 1];

    float ax = 0.f, ay = 0.f, az = 0.f, aw = 0.f;
    if (e > s) {
        int i = s + eg;
        const int nfull = (e - s) / EPW;
        int cc = col[min(i, e - 1)];
#pragma unroll 2
        for (int b = 0; b < nfull; ++b) {
            int cn = col[min(i + EPW, e - 1)];
            const __half* p = X + (size_t)cc * FEATS + fl * 4;
            float2 f01 = __half22float2(*(const __half2*)p);
            float2 f23 = __half22float2(*(const __half2*)(p + 2));
            ax += f01.x; ay += f01.y; az += f23.x; aw += f23.y;
            cc = cn; i += EPW;
        }
        if (i < e) {
            const __half* p = X + (size_t)cc * FEATS + fl * 4;
            float2 f01 = __half22float2(*(const __half2*)p);
            float2 f23 = __half22float2(*(const __half2*)(p + 2));
            ax += f01.x; ay += f01.y; az += f23.x; aw += f23.y;
        }
    }
#pragma unroll
    for (int m = LPE; m < 64; m <<= 1) {
        ax += __shfl_xor(ax, m);
        ay += __shfl_xor(ay, m);
        az += __shfl_xor(az, m);
        aw += __shfl_xor(aw, m);
    }
    if (eg == 0) {
        if (EPI != 0) {
            float sc = inv_deg[node];
            ax = ax * sc + bias[fl * 4 + 0];
            ay = ay * sc + bias[fl * 4 + 1];
            az = az * sc + bias[fl * 4 + 2];
            aw = aw * sc + bias[fl * 4 + 3];
            if (EPI == 1) {
                ax = fmaxf(ax, 0.f); ay = fmaxf(ay, 0.f);
                az = fmaxf(az, 0.f); aw = fmaxf(aw, 0.f);
            }
        }
        store4(&out[(size_t)node * FEATS + fl * 4], ax, ay, az, aw);
    }
}

// Layer-0 GEMM on matrix cores: H[nrows x 64] = feat[nrows x 256] @ W0 (fp16 in, f32 acc).
__global__ __launch_bounds__(256) void gemm0_mfma(const float* __restrict__ A, const __half* __restrict__ W0t,
                                                  __half* __restrict__ out, int nrows) {
    constexpr int LDH = 280;   // 560B row stride: 16B aligned, bank-skewed
    __shared__ _Float16 As[64][LDH];
    __shared__ _Float16 Bs[64][LDH];
    const int t = threadIdx.x;
    const int wave = t >> 6, lane = t & 63;
    const int row0 = blockIdx.x * 64;

#pragma unroll
    for (int l = 0; l < 16; ++l) {
        int fid = t + l * 256;
        int r = fid >> 6, c4 = fid & 63;
        int grow = row0 + r;
        int gr = grow < nrows ? grow : 0;
        float4 v = *(const float4*)&A[(size_t)gr * 256 + c4 * 4];
        _Float16* p = &As[r][c4 * 4];
        p[0] = (_Float16)v.x; p[1] = (_Float16)v.y;
        p[2] = (_Float16)v.z; p[3] = (_Float16)v.w;
    }
#pragma unroll
    for (int l = 0; l < 8; ++l) {
        int fid = t + l * 256;
        int r = fid >> 5, c8 = fid & 31;
        *(half8*)&Bs[r][c8 * 8] = *(const half8*)&W0t[r * 256 + c8 * 8];
    }
    __syncthreads();

    const int ar = wave * 16 + (lane & 15);
    const int kh = (lane >> 4) * 8;
    floatx4 acc0 = {0.f, 0.f, 0.f, 0.f}, acc1 = acc0, acc2 = acc0, acc3 = acc0;
#pragma unroll
    for (int ks = 0; ks < 8; ++ks) {
        const int k0 = ks * 32 + kh;
        half8 a = *(half8*)&As[ar][k0];
        half8 b0 = *(half8*)&Bs[ 0 + (lane & 15)][k0];
        half8 b1 = *(half8*)&Bs[16 + (lane & 15)][k0];
        half8 b2 = *(half8*)&Bs[32 + (lane & 15)][k0];
        half8 b3 = *(half8*)&Bs[48 + (lane & 15)][k0];
        acc0 = __builtin_amdgcn_mfma_f32_16x16x32_f16(a, b0, acc0, 0, 0, 0);
        acc1 = __builtin_amdgcn_mfma_f32_16x16x32_f16(a, b1, acc1, 0, 0, 0);
        acc2 = __builtin_amdgcn_mfma_f32_16x16x32_f16(a, b2, acc2, 0, 0, 0);
        acc3 = __builtin_amdgcn_mfma_f32_16x16x32_f16(a, b3, acc3, 0, 0, 0);
    }

    const int cc = lane & 15;
    const int rb = wave * 16 + (lane >> 4) * 4;
#pragma unroll
    for (int i = 0; i < 4; ++i) {
        int r = row0 + rb + i;
        if (r < nrows) {
            __half* po = &out[(size_t)r * 64];
            po[ 0 + cc] = __float2half(acc0[i]);
            po[16 + cc] = __float2half(acc1[i]);
            po[32 + cc] = __float2half(acc2[i]);
            po[48 + cc] = __float2half(acc3[i]);
        }
    }
}

// Fused layers 1+2 GEMM, full MFMA: X2 = relu((A2@W1)*inv+b1) (LDS, fp16);
// H2 = X2@W2 -> out (fp16, 32 cols).
__global__ __launch_bounds__(256) void gemm12_mfma(const __half* __restrict__ A2, const __half* __restrict__ W1t,
                                                   const float* __restrict__ b1, const __half* __restrict__ W2t,
                                                   const float* __restrict__ inv_deg,
                                                   __half* __restrict__ out, int nrows) {
    constexpr int LDH = 72;    // 144B row stride: 16B aligned, bank-skewed
    __shared__ _Float16 As [64][LDH];
    __shared__ _Float16 B1s[64][LDH];
    __shared__ _Float16 B2s[32][LDH];
    __shared__ _Float16 X2s[64][LDH];
    const int t = threadIdx.x;
    const int wave = t >> 6, lane = t & 63;
    const int row0 = blockIdx.x * 64;

#pragma unroll
    for (int l = 0; l < 2; ++l) {
        int fid = t + l * 256;
        int r = fid >> 3, c8 = fid & 7;
        int grow = row0 + r;
        int gr = grow < nrows ? grow : 0;
        *(half8*)&As[r][c8 * 8] = *(const half8*)&A2[(size_t)gr * 64 + c8 * 8];
    }
#pragma unroll
    for (int l = 0; l < 2; ++l) {
        int fid = t + l * 256;
        int r = fid >> 3, c8 = fid & 7;
        *(half8*)&B1s[r][c8 * 8] = *(const half8*)&W1t[r * 64 + c8 * 8];
    }
    {
        int r = t >> 3, c8 = t & 7;
        *(half8*)&B2s[r][c8 * 8] = *(const half8*)&W2t[r * 64 + c8 * 8];
    }
    __syncthreads();

    const int ar = wave * 16 + (lane & 15);
    const int kh = (lane >> 4) * 8;
    const int cc = lane & 15;
    const int rb = wave * 16 + (lane >> 4) * 4;

    // Phase 1: acc = A2 @ W1 (K=64)
    floatx4 acc0 = {0.f, 0.f, 0.f, 0.f}, acc1 = acc0, acc2 = acc0, acc3 = acc0;
#pragma unroll
    for (int ks = 0; ks < 2; ++ks) {
        const int k0 = ks * 32 + kh;
        half8 a = *(half8*)&As[ar][k0];
        half8 b0 = *(half8*)&B1s[ 0 + (lane & 15)][k0];
        half8 b1v = *(half8*)&B1s[16 + (lane & 15)][k0];
        half8 b2v = *(half8*)&B1s[32 + (lane & 15)][k0];
        half8 b3v = *(half8*)&B1s[48 + (lane & 15)][k0];
        acc0 = __builtin_amdgcn_mfma_f32_16x16x32_f16(a, b0, acc0, 0, 0, 0);
        acc1 = __builtin_amdgcn_mfma_f32_16x16x32_f16(a, b1v, acc1, 0, 0, 0);
        acc2 = __builtin_amdgcn_mfma_f32_16x16x32_f16(a, b2v, acc2, 0, 0, 0);
        acc3 = __builtin_amdgcn_mfma_f32_16x16x32_f16(a, b3v, acc3, 0, 0, 0);
    }

    // Epilogue 1: X2 = relu(acc*inv + b1) -> LDS fp16 (C/D: col=cc, row=rb+i).
#pragma unroll
    for (int i = 0; i < 4; ++i) {
        int r = row0 + rb + i;
        float sc = (r < nrows) ? inv_deg[r] : 0.f;
        X2s[rb + i][ 0 + cc] = (_Float16)fmaxf(acc0[i] * sc + b1[ 0 + cc], 0.f);
        X2s[rb + i][16 + cc] = (_Float16)fmaxf(acc1[i] * sc + b1[16 + cc], 0.f);
        X2s[rb + i][32 + cc] = (_Float16)fmaxf(acc2[i] * sc + b1[32 + cc], 0.f);
        X2s[rb + i][48 + cc] = (_Float16)fmaxf(acc3[i] * sc + b1[48 + cc], 0.f);
    }
    __syncthreads();

    // Phase 2: H2 = X2 @ W2 (64x64 @ 64x32)
    floatx4 acc4 = {0.f, 0.f, 0.f, 0.f}, acc5 = acc4;
#pragma unroll
    for (int ks = 0; ks < 2; ++ks) {
        const int k0 = ks * 32 + kh;
        half8 a = *(half8*)&X2s[ar][k0];
        half8 c0 = *(half8*)&B2s[ 0 + (lane & 15)][k0];
        half8 c1 = *(half8*)&B2s[16 + (lane & 15)][k0];
        acc4 = __builtin_amdgcn_mfma_f32_16x16x32_f16(a, c0, acc4, 0, 0, 0);
        acc5 = __builtin_amdgcn_mfma_f32_16x16x32_f16(a, c1, acc5, 0, 0, 0);
    }

#pragma unroll
    for (int i = 0; i < 4; ++i) {
        int r = row0 + rb + i;
        if (r < nrows) {
            __half* po = &out[(size_t)r * 32];
            po[ 0 + cc] = __float2half(acc4[i]);
            po[16 + cc] = __float2half(acc5[i]);
        }
    }
}

extern "C" void kernel_launch(void* const* d_in, const int* in_sizes, int n_in,
                              void* d_out, int out_size, void* d_ws, size_t ws_size,
                              hipStream_t stream) {
    const float* feat = (const float*)d_in[0];
    const float* W0   = (const float*)d_in[1];
    const float* b0   = (const float*)d_in[2];
    const float* W1   = (const float*)d_in[3];
    const float* b1   = (const float*)d_in[4];
    const float* W2   = (const float*)d_in[5];
    const float* b2   = (const float*)d_in[6];
    const int*   src  = (const int*)d_in[7];
    const int*   dstv = (const int*)d_in[8];

    const int n = in_sizes[0] / 256;   // 100000
    const int e = in_sizes[7];         // 1600000

    const int nb    = (n + 127) >> NB_SHIFT;          // 782 buckets
    const int nblkA = (e + EPB_A - 1) / EPB_A;        // 782 blocks
    const int nblkB = (e + EPB_B - 1) / EPB_B;        // 196 blocks

    // Workspace carve-up (256B aligned).
    char* base_p = (char*)d_ws;
    size_t off = 0;
    auto alloc = [&](size_t bytes) -> char* {
        char* p = base_p + off;
        off += (bytes + 255) & ~(size_t)255;
        return p;
    };
    float*  invd   = (float*)alloc((size_t)n * 4);
    int*    rowptr = (int*)alloc((size_t)(n + 1) * 4);
    int*    bbase  = (int*)alloc((size_t)(MAXNB + 1) * 4);
    int*    totals = (int*)alloc((size_t)MAXNB * 4);
    __half* W0t    = (__half*)alloc((size_t)256 * 64 * 2);
    __half* W1t    = (__half*)alloc((size_t)64 * 64 * 2);
    __half* W2t    = (__half*)alloc((size_t)32 * 64 * 2);
    int*    col    = (int*)alloc((size_t)e * 4);          // C_T aliases col (nb*nblkA=2.45MB < 6.4MB)
    __half* bufH1  = (__half*)alloc((size_t)n * 64 * 2);  // H; later A2. sorted_pk aliases.
    __half* bufH2  = (__half*)alloc((size_t)n * 64 * 2);  // X1; later H2 (32f)
    (void)ws_size;

    int* C_T       = col;           // dead before col is written
    int* sorted_pk = (int*)bufH1;   // e*4 B (6.4MB) — dead before gemm0 writes bufH1

    // --- CSR build (bucketed sort, no global atomics) ---
    passA_hist   <<<nblkA, 256, 0, stream>>>(dstv, C_T, nb, nblkA, e);
    bucket_prefix<<<nb,    256, 0, stream>>>(C_T, totals, nblkA);
    scan_cvt     <<<89,    256, 0, stream>>>(totals, bbase, rowptr, nb, n, e,
                                             W0, W1, W2, W0t, W1t, W2t);
    passB_scatter<<<nblkB, 256, 0, stream>>>(src, dstv, C_T, bbase, sorted_pk, nb, nblkA, e);
    passC_build  <<<nb,    256, 0, stream>>>(sorted_pk, bbase, rowptr, col, invd, n);

    const int gemm_blocks = (n + 63) / 64;
    const int agg_blocks  = (n + 3) / 4;   // one wave per node, 4 waves/block

    // --- Layer 0: H = feat@W0 (MFMA) ; X1 = relu(agg(H)*inv + b0) ---
    gemm0_mfma<<<gemm_blocks, 256, 0, stream>>>(feat, W0t, bufH1, n);
    agg_kernel<64, 1, __half><<<agg_blocks, 256, 0, stream>>>(bufH1, col, rowptr, invd, b0, bufH2, n);

    // --- Layer 1: A2 = agg(X1) ; fused MFMA: X2 = relu((A2@W1)*inv+b1); H2 = X2@W2 ---
    agg_kernel<64, 0, __half><<<agg_blocks, 256, 0, stream>>>(bufH2, col, rowptr, nullptr, nullptr, bufH1, n);
    gemm12_mfma<<<gemm_blocks, 256, 0, stream>>>(bufH1, W1t, b1, W2t, invd, bufH2, n);

    // --- Layer 2: out = agg(H2)*inv + b2 (32f gather over 6.4MB) ---
    agg_kernel<32, 2, float><<<agg_blocks, 256, 0, stream>>>(bufH2, col, rowptr, invd, b2, (float*)d_out, n);
}

// Round 11
// 185.481 us; speedup vs baseline: 1.2565x; 1.0264x over previous
//
#include <hip/hip_runtime.h>
#include <hip/hip_bf16.h>
#include <hip/hip_fp16.h>

// GCN: 3 layers over fixed graph (N=100000 nodes, E=1600000 edges).
// CSR build via bucketed sort (passA EPB=2048 / passB EPB=8192, int4 reads).
// Gather aggs: 16B/lane half8 gathers -> 8 (64f) / 16 (32f) edges in
// flight per wave-issue, branchless pipelined. GEMMs on matrix cores.

constexpr int NB_SHIFT = 7;          // 128 nodes per bucket
constexpr int EPB_A = 2048;          // passA edges per block (782 blocks)
constexpr int EPB_B = 8192;          // passB edges per block (196 blocks)
constexpr int MAXNB = 800;           // >= ceil(100000/128)=782

using half8   = __attribute__((ext_vector_type(8))) _Float16;
using floatx4 = __attribute__((ext_vector_type(4))) float;

// Pass A: per-block LDS histogram over buckets -> C_T[bucket][blockA] counts.
__global__ __launch_bounds__(256) void passA_hist(const int* __restrict__ dst, int* __restrict__ C_T,
                                                  int nb, int nblkA, int n_edges) {
    __shared__ int h[MAXNB];
    for (int i = threadIdx.x; i < nb; i += 256) h[i] = 0;
    __syncthreads();
    const int e0 = blockIdx.x * EPB_A;
    const int e1 = min(e0 + EPB_A, n_edges);
    for (int i4 = e0 + threadIdx.x * 4; i4 < e1; i4 += 1024) {
        int4 d4 = *(const int4*)&dst[i4];
        atomicAdd(&h[d4.x >> NB_SHIFT], 1);
        atomicAdd(&h[d4.y >> NB_SHIFT], 1);
        atomicAdd(&h[d4.z >> NB_SHIFT], 1);
        atomicAdd(&h[d4.w >> NB_SHIFT], 1);
    }
    __syncthreads();
    for (int i = threadIdx.x; i < nb; i += 256)
        C_T[i * nblkA + blockIdx.x] = h[i];
}

// Per-bucket exclusive scan across blockA columns (in place, nblkA <= 1024); totals out.
__global__ __launch_bounds__(256) void bucket_prefix(int* __restrict__ C_T, int* __restrict__ totals,
                                                     int nblkA) {
    __shared__ int s[256];
    const int b = blockIdx.x, t = threadIdx.x;
    int v[4]; int ts = 0;
#pragma unroll
    for (int j = 0; j < 4; ++j) { int i = t * 4 + j; v[j] = (i < nblkA) ? C_T[b * nblkA + i] : 0; ts += v[j]; }
    s[t] = ts; __syncthreads();
    for (int off = 1; off < 256; off <<= 1) {
        int x = (t >= off) ? s[t - off] : 0;
        __syncthreads();
        s[t] += x;
        __syncthreads();
    }
    int run = s[t] - ts;
#pragma unroll
    for (int j = 0; j < 4; ++j) { int i = t * 4 + j; if (i < nblkA) C_T[b * nblkA + i] = run; run += v[j]; }
    if (t == 255) totals[b] = s[255];
}

// Block 0: exclusive scan of bucket totals -> base[nb+1], rowptr[n]=E.
// Blocks 1..88: transpose+convert weights to fp16.
__global__ __launch_bounds__(256) void scan_cvt(const int* __restrict__ totals, int* __restrict__ base_out,
                                                int* __restrict__ rowptr, int nb, int n, int n_edges,
                                                const float* __restrict__ W0, const float* __restrict__ W1,
                                                const float* __restrict__ W2,
                                                __half* __restrict__ W0t, __half* __restrict__ W1t,
                                                __half* __restrict__ W2t) {
    const int t = threadIdx.x;
    if (blockIdx.x == 0) {
        __shared__ int s[256];
        int v[4]; int ts = 0;
#pragma unroll
        for (int j = 0; j < 4; ++j) { int i = t * 4 + j; v[j] = (i < nb) ? totals[i] : 0; ts += v[j]; }
        s[t] = ts; __syncthreads();
        for (int off = 1; off < 256; off <<= 1) {
            int x = (t >= off) ? s[t - off] : 0;
            __syncthreads();
            s[t] += x;
            __syncthreads();
        }
        int run = s[t] - ts;
#pragma unroll
        for (int j = 0; j < 4; ++j) { int i = t * 4 + j; if (i < nb) base_out[i] = run; run += v[j]; }
        if (t == 255) base_out[nb] = s[255];
        if (t == 0) rowptr[n] = n_edges;
    } else {
        const int b = blockIdx.x - 1;
        if (b < 64) {        // W0 [256][64] -> W0t [64][256]
            int o = b * 256 + t;
            W0t[o] = __float2half(W0[(o & 255) * 64 + (o >> 8)]);
        } else if (b < 80) { // W1 [64][64] -> W1t [64][64]
            int o = (b - 64) * 256 + t;
            W1t[o] = __float2half(W1[(o & 63) * 64 + (o >> 6)]);
        } else {             // W2 [64][32] -> W2t [32][64]
            int o = (b - 80) * 256 + t;
            W2t[o] = __float2half(W2[(o & 63) * 32 + (o >> 6)]);
        }
    }
}

// Pass B: scatter packed (ldst<<17)|src into bucket order using LDS cursors.
__global__ __launch_bounds__(256) void passB_scatter(const int* __restrict__ src, const int* __restrict__ dst,
                                                     const int* __restrict__ C_T, const int* __restrict__ base,
                                                     int* __restrict__ sorted_pk, int nb, int nblkA, int n_edges) {
    __shared__ int cur[MAXNB];
    const int blk = blockIdx.x;
    const int colA = blk * (EPB_B / EPB_A);
    for (int i = threadIdx.x; i < nb; i += 256) cur[i] = base[i] + C_T[i * nblkA + colA];
    __syncthreads();
    const int e0 = blk * EPB_B;
    const int e1 = min(e0 + EPB_B, n_edges);
    for (int i4 = e0 + threadIdx.x * 4; i4 < e1; i4 += 1024) {
        int4 s4 = *(const int4*)&src[i4];
        int4 d4 = *(const int4*)&dst[i4];
        int p0 = atomicAdd(&cur[d4.x >> NB_SHIFT], 1);
        sorted_pk[p0] = ((d4.x & 127) << 17) | s4.x;
        int p1 = atomicAdd(&cur[d4.y >> NB_SHIFT], 1);
        sorted_pk[p1] = ((d4.y & 127) << 17) | s4.y;
        int p2 = atomicAdd(&cur[d4.z >> NB_SHIFT], 1);
        sorted_pk[p2] = ((d4.z & 127) << 17) | s4.z;
        int p3 = atomicAdd(&cur[d4.w >> NB_SHIFT], 1);
        sorted_pk[p3] = ((d4.w & 127) << 17) | s4.w;
    }
}

// Pass C: per-bucket counting sort in LDS -> rowptr, col, inv_deg.
__global__ __launch_bounds__(256) void passC_build(const int* __restrict__ sorted_pk, const int* __restrict__ base,
                                                   int* __restrict__ rowptr, int* __restrict__ col,
                                                   float* __restrict__ invd, int n) {
    __shared__ int degl[128];
    __shared__ int s[256];
    __shared__ int curl[128];
    const int b = blockIdx.x, t = threadIdx.x;
    const int node0 = b << NB_SHIFT;
    const int nn = min(128, n - node0);
    const int e0 = base[b], e1 = base[b + 1];
    if (t < 128) degl[t] = 0;
    __syncthreads();
    for (int i = e0 + t; i < e1; i += 256)
        atomicAdd(&degl[sorted_pk[i] >> 17], 1);
    __syncthreads();
    int d = (t < 128) ? degl[t] : 0;
    s[t] = d; __syncthreads();
    for (int off = 1; off < 128; off <<= 1) {
        int x = (t >= off) ? s[t - off] : 0;
        __syncthreads();
        s[t] += x;
        __syncthreads();
    }
    if (t < 128) {
        int excl = s[t] - d;
        curl[t] = excl;
        if (t < nn) {
            rowptr[node0 + t] = e0 + excl;
            invd[node0 + t] = 1.0f / (float)(d > 0 ? d : 1);
        }
    }
    __syncthreads();
    for (int i = e0 + t; i < e1; i += 256) {
        int pk = sorted_pk[i];
        int p = atomicAdd(&curl[pk >> 17], 1);
        col[e0 + p] = pk & 0x1FFFF;
    }
}

// Gather-aggregate: one node per wave; lane = (edge_slot, feat_octet).
// 16B/lane half8 gathers: LPE = FEATS/8 lanes per edge, EPW = 64/LPE edges
// in flight per issue (64f: 8, 32f: 16). Branchless pipelined col prefetch.
// EPI: 0 = plain sum; 1 = relu(sum*inv_deg + bias); 2 = sum*inv_deg + bias.
template <int FEATS, int EPI, typename OutT>
__global__ __launch_bounds__(256) void agg_kernel(const __half* __restrict__ X, const int* __restrict__ col,
                                                  const int* __restrict__ rowptr,
                                                  const float* __restrict__ inv_deg,
                                                  const float* __restrict__ bias,
                                                  OutT* __restrict__ out, int n) {
    constexpr int LPE = FEATS / 8;   // lanes per edge (8 or 4)
    constexpr int EPW = 64 / LPE;    // edges per wave-issue (8 or 16)
    const int node = blockIdx.x * 4 + (threadIdx.x >> 6);
    if (node >= n) return;
    const int lane = threadIdx.x & 63;
    const int eg = lane / LPE;       // edge slot
    const int fl = lane % LPE;       // feature-octet index
    const int s = rowptr[node], e = rowptr[node + 1];

    float acc[8] = {};
    if (e > s) {
        int i = s + eg;
        const int nfull = (e - s) / EPW;
        int cc = col[min(i, e - 1)];
#pragma unroll 2
        for (int b = 0; b < nfull; ++b) {
            int cn = col[min(i + EPW, e - 1)];   // prefetch next batch (clamped, branch-free)
            half8 h = *(const half8*)(X + (size_t)cc * FEATS + fl * 8);
#pragma unroll
            for (int j = 0; j < 8; ++j) acc[j] += (float)h[j];
            cc = cn; i += EPW;
        }
        if (i < e) {                             // masked tail batch
            half8 h = *(const half8*)(X + (size_t)cc * FEATS + fl * 8);
#pragma unroll
            for (int j = 0; j < 8; ++j) acc[j] += (float)h[j];
        }
    }
    // fold edge slots: lanes fl, fl+LPE, ... hold the same feature octet
#pragma unroll
    for (int m = LPE; m < 64; m <<= 1) {
#pragma unroll
        for (int j = 0; j < 8; ++j) acc[j] += __shfl_xor(acc[j], m);
    }
    if (eg == 0) {
        if (EPI != 0) {
            float sc = inv_deg[node];
#pragma unroll
            for (int j = 0; j < 8; ++j) {
                acc[j] = acc[j] * sc + bias[fl * 8 + j];
                if (EPI == 1) acc[j] = fmaxf(acc[j], 0.f);
            }
        }
        if constexpr (sizeof(OutT) == 2) {   // fp16 out: one 16B store
            half8 hv;
#pragma unroll
            for (int j = 0; j < 8; ++j) hv[j] = (_Float16)acc[j];
            *(half8*)((__half*)out + (size_t)node * FEATS + fl * 8) = hv;
        } else {                             // f32 out: two 16B stores
            float* po = (float*)out + (size_t)node * FEATS + fl * 8;
            *(float4*)po       = make_float4(acc[0], acc[1], acc[2], acc[3]);
            *(float4*)(po + 4) = make_float4(acc[4], acc[5], acc[6], acc[7]);
        }
    }
}

// Layer-0 GEMM on matrix cores: H[nrows x 64] = feat[nrows x 256] @ W0 (fp16 in, f32 acc).
__global__ __launch_bounds__(256) void gemm0_mfma(const float* __restrict__ A, const __half* __restrict__ W0t,
                                                  __half* __restrict__ out, int nrows) {
    constexpr int LDH = 280;   // 560B row stride: 16B aligned, bank-skewed
    __shared__ _Float16 As[64][LDH];
    __shared__ _Float16 Bs[64][LDH];
    const int t = threadIdx.x;
    const int wave = t >> 6, lane = t & 63;
    const int row0 = blockIdx.x * 64;

#pragma unroll
    for (int l = 0; l < 16; ++l) {
        int fid = t + l * 256;
        int r = fid >> 6, c4 = fid & 63;
        int grow = row0 + r;
        int gr = grow < nrows ? grow : 0;
        float4 v = *(const float4*)&A[(size_t)gr * 256 + c4 * 4];
        _Float16* p = &As[r][c4 * 4];
        p[0] = (_Float16)v.x; p[1] = (_Float16)v.y;
        p[2] = (_Float16)v.z; p[3] = (_Float16)v.w;
    }
#pragma unroll
    for (int l = 0; l < 8; ++l) {
        int fid = t + l * 256;
        int r = fid >> 5, c8 = fid & 31;
        *(half8*)&Bs[r][c8 * 8] = *(const half8*)&W0t[r * 256 + c8 * 8];
    }
    __syncthreads();

    const int ar = wave * 16 + (lane & 15);
    const int kh = (lane >> 4) * 8;
    floatx4 acc0 = {0.f, 0.f, 0.f, 0.f}, acc1 = acc0, acc2 = acc0, acc3 = acc0;
#pragma unroll
    for (int ks = 0; ks < 8; ++ks) {
        const int k0 = ks * 32 + kh;
        half8 a = *(half8*)&As[ar][k0];
        half8 b0 = *(half8*)&Bs[ 0 + (lane & 15)][k0];
        half8 b1 = *(half8*)&Bs[16 + (lane & 15)][k0];
        half8 b2 = *(half8*)&Bs[32 + (lane & 15)][k0];
        half8 b3 = *(half8*)&Bs[48 + (lane & 15)][k0];
        acc0 = __builtin_amdgcn_mfma_f32_16x16x32_f16(a, b0, acc0, 0, 0, 0);
        acc1 = __builtin_amdgcn_mfma_f32_16x16x32_f16(a, b1, acc1, 0, 0, 0);
        acc2 = __builtin_amdgcn_mfma_f32_16x16x32_f16(a, b2, acc2, 0, 0, 0);
        acc3 = __builtin_amdgcn_mfma_f32_16x16x32_f16(a, b3, acc3, 0, 0, 0);
    }

    const int cc = lane & 15;
    const int rb = wave * 16 + (lane >> 4) * 4;
#pragma unroll
    for (int i = 0; i < 4; ++i) {
        int r = row0 + rb + i;
        if (r < nrows) {
            __half* po = &out[(size_t)r * 64];
            po[ 0 + cc] = __float2half(acc0[i]);
            po[16 + cc] = __float2half(acc1[i]);
            po[32 + cc] = __float2half(acc2[i]);
            po[48 + cc] = __float2half(acc3[i]);
        }
    }
}

// Fused layers 1+2 GEMM, full MFMA: X2 = relu((A2@W1)*inv+b1) (LDS, fp16);
// H2 = X2@W2 -> out (fp16, 32 cols).
__global__ __launch_bounds__(256) void gemm12_mfma(const __half* __restrict__ A2, const __half* __restrict__ W1t,
                                                   const float* __restrict__ b1, const __half* __restrict__ W2t,
                                                   const float* __restrict__ inv_deg,
                                                   __half* __restrict__ out, int nrows) {
    constexpr int LDH = 72;    // 144B row stride: 16B aligned, bank-skewed
    __shared__ _Float16 As [64][LDH];
    __shared__ _Float16 B1s[64][LDH];
    __shared__ _Float16 B2s[32][LDH];
    __shared__ _Float16 X2s[64][LDH];
    const int t = threadIdx.x;
    const int wave = t >> 6, lane = t & 63;
    const int row0 = blockIdx.x * 64;

#pragma unroll
    for (int l = 0; l < 2; ++l) {
        int fid = t + l * 256;
        int r = fid >> 3, c8 = fid & 7;
        int grow = row0 + r;
        int gr = grow < nrows ? grow : 0;
        *(half8*)&As[r][c8 * 8] = *(const half8*)&A2[(size_t)gr * 64 + c8 * 8];
    }
#pragma unroll
    for (int l = 0; l < 2; ++l) {
        int fid = t + l * 256;
        int r = fid >> 3, c8 = fid & 7;
        *(half8*)&B1s[r][c8 * 8] = *(const half8*)&W1t[r * 64 + c8 * 8];
    }
    {
        int r = t >> 3, c8 = t & 7;
        *(half8*)&B2s[r][c8 * 8] = *(const half8*)&W2t[r * 64 + c8 * 8];
    }
    __syncthreads();

    const int ar = wave * 16 + (lane & 15);
    const int kh = (lane >> 4) * 8;
    const int cc = lane & 15;
    const int rb = wave * 16 + (lane >> 4) * 4;

    // Phase 1: acc = A2 @ W1 (K=64)
    floatx4 acc0 = {0.f, 0.f, 0.f, 0.f}, acc1 = acc0, acc2 = acc0, acc3 = acc0;
#pragma unroll
    for (int ks = 0; ks < 2; ++ks) {
        const int k0 = ks * 32 + kh;
        half8 a = *(half8*)&As[ar][k0];
        half8 b0 = *(half8*)&B1s[ 0 + (lane & 15)][k0];
        half8 b1v = *(half8*)&B1s[16 + (lane & 15)][k0];
        half8 b2v = *(half8*)&B1s[32 + (lane & 15)][k0];
        half8 b3v = *(half8*)&B1s[48 + (lane & 15)][k0];
        acc0 = __builtin_amdgcn_mfma_f32_16x16x32_f16(a, b0, acc0, 0, 0, 0);
        acc1 = __builtin_amdgcn_mfma_f32_16x16x32_f16(a, b1v, acc1, 0, 0, 0);
        acc2 = __builtin_amdgcn_mfma_f32_16x16x32_f16(a, b2v, acc2, 0, 0, 0);
        acc3 = __builtin_amdgcn_mfma_f32_16x16x32_f16(a, b3v, acc3, 0, 0, 0);
    }

    // Epilogue 1: X2 = relu(acc*inv + b1) -> LDS fp16 (C/D: col=cc, row=rb+i).
#pragma unroll
    for (int i = 0; i < 4; ++i) {
        int r = row0 + rb + i;
        float sc = (r < nrows) ? inv_deg[r] : 0.f;
        X2s[rb + i][ 0 + cc] = (_Float16)fmaxf(acc0[i] * sc + b1[ 0 + cc], 0.f);
        X2s[rb + i][16 + cc] = (_Float16)fmaxf(acc1[i] * sc + b1[16 + cc], 0.f);
        X2s[rb + i][32 + cc] = (_Float16)fmaxf(acc2[i] * sc + b1[32 + cc], 0.f);
        X2s[rb + i][48 + cc] = (_Float16)fmaxf(acc3[i] * sc + b1[48 + cc], 0.f);
    }
    __syncthreads();

    // Phase 2: H2 = X2 @ W2 (64x64 @ 64x32)
    floatx4 acc4 = {0.f, 0.f, 0.f, 0.f}, acc5 = acc4;
#pragma unroll
    for (int ks = 0; ks < 2; ++ks) {
        const int k0 = ks * 32 + kh;
        half8 a = *(half8*)&X2s[ar][k0];
        half8 c0 = *(half8*)&B2s[ 0 + (lane & 15)][k0];
        half8 c1 = *(half8*)&B2s[16 + (lane & 15)][k0];
        acc4 = __builtin_amdgcn_mfma_f32_16x16x32_f16(a, c0, acc4, 0, 0, 0);
        acc5 = __builtin_amdgcn_mfma_f32_16x16x32_f16(a, c1, acc5, 0, 0, 0);
    }

#pragma unroll
    for (int i = 0; i < 4; ++i) {
        int r = row0 + rb + i;
        if (r < nrows) {
            __half* po = &out[(size_t)r * 32];
            po[ 0 + cc] = __float2half(acc4[i]);
            po[16 + cc] = __float2half(acc5[i]);
        }
    }
}

extern "C" void kernel_launch(void* const* d_in, const int* in_sizes, int n_in,
                              void* d_out, int out_size, void* d_ws, size_t ws_size,
                              hipStream_t stream) {
    const float* feat = (const float*)d_in[0];
    const float* W0   = (const float*)d_in[1];
    const float* b0   = (const float*)d_in[2];
    const float* W1   = (const float*)d_in[3];
    const float* b1   = (const float*)d_in[4];
    const float* W2   = (const float*)d_in[5];
    const float* b2   = (const float*)d_in[6];
    const int*   src  = (const int*)d_in[7];
    const int*   dstv = (const int*)d_in[8];

    const int n = in_sizes[0] / 256;   // 100000
    const int e = in_sizes[7];         // 1600000

    const int nb    = (n + 127) >> NB_SHIFT;          // 782 buckets
    const int nblkA = (e + EPB_A - 1) / EPB_A;        // 782 blocks
    const int nblkB = (e + EPB_B - 1) / EPB_B;        // 196 blocks

    // Workspace carve-up (256B aligned).
    char* base_p = (char*)d_ws;
    size_t off = 0;
    auto alloc = [&](size_t bytes) -> char* {
        char* p = base_p + off;
        off += (bytes + 255) & ~(size_t)255;
        return p;
    };
    float*  invd   = (float*)alloc((size_t)n * 4);
    int*    rowptr = (int*)alloc((size_t)(n + 1) * 4);
    int*    bbase  = (int*)alloc((size_t)(MAXNB + 1) * 4);
    int*    totals = (int*)alloc((size_t)MAXNB * 4);
    __half* W0t    = (__half*)alloc((size_t)256 * 64 * 2);
    __half* W1t    = (__half*)alloc((size_t)64 * 64 * 2);
    __half* W2t    = (__half*)alloc((size_t)32 * 64 * 2);
    int*    col    = (int*)alloc((size_t)e * 4);          // C_T aliases col
    __half* bufH1  = (__half*)alloc((size_t)n * 64 * 2);  // H; later A2. sorted_pk aliases.
    __half* bufH2  = (__half*)alloc((size_t)n * 64 * 2);  // X1; later H2 (32f)
    (void)ws_size;

    int* C_T       = col;           // dead before col is written
    int* sorted_pk = (int*)bufH1;   // e*4 B (6.4MB) — dead before gemm0 writes bufH1

    // --- CSR build (bucketed sort, no global atomics) ---
    passA_hist   <<<nblkA, 256, 0, stream>>>(dstv, C_T, nb, nblkA, e);
    bucket_prefix<<<nb,    256, 0, stream>>>(C_T, totals, nblkA);
    scan_cvt     <<<89,    256, 0, stream>>>(totals, bbase, rowptr, nb, n, e,
                                             W0, W1, W2, W0t, W1t, W2t);
    passB_scatter<<<nblkB, 256, 0, stream>>>(src, dstv, C_T, bbase, sorted_pk, nb, nblkA, e);
    passC_build  <<<nb,    256, 0, stream>>>(sorted_pk, bbase, rowptr, col, invd, n);

    const int gemm_blocks = (n + 63) / 64;
    const int agg_blocks  = (n + 3) / 4;   // one wave per node, 4 waves/block

    // --- Layer 0: H = feat@W0 (MFMA) ; X1 = relu(agg(H)*inv + b0) ---
    gemm0_mfma<<<gemm_blocks, 256, 0, stream>>>(feat, W0t, bufH1, n);
    agg_kernel<64, 1, __half><<<agg_blocks, 256, 0, stream>>>(bufH1, col, rowptr, invd, b0, bufH2, n);

    // --- Layer 1: A2 = agg(X1) ; fused MFMA: X2 = relu((A2@W1)*inv+b1); H2 = X2@W2 ---
    agg_kernel<64, 0, __half><<<agg_blocks, 256, 0, stream>>>(bufH2, col, rowptr, nullptr, nullptr, bufH1, n);
    gemm12_mfma<<<gemm_blocks, 256, 0, stream>>>(bufH1, W1t, b1, W2t, invd, bufH2, n);

    // --- Layer 2: out = agg(H2)*inv + b2 (32f gather over 6.4MB) ---
    agg_kernel<32, 2, float><<<agg_blocks, 256, 0, stream>>>(bufH2, col, rowptr, invd, b2, (float*)d_out, n);
}